// Round 1
// 360.520 us; speedup vs baseline: 1.2216x; 1.2216x over previous
//
#include <hip/hip_runtime.h>
#include <math.h>

#define HID 2048
#define ITR 1024
#define NEXP 8
#define TOPK 2
#define NTOK 2048
#define NSLOT (NTOK * TOPK)
#define MAXTT 40        // max 128-row tiles across experts (bound 4096/128+7=39)
#define SLOTS 80        // per-XCD slot count for block tables (bound 2*39=78)

typedef __attribute__((ext_vector_type(8))) short short8;
typedef __attribute__((ext_vector_type(4))) float f32x4;

__device__ __forceinline__ unsigned short f2bf(float f) {
    unsigned u = __float_as_uint(f);
    u += 0x7FFFu + ((u >> 16) & 1u);
    return (unsigned short)(u >> 16);
}

// async global->LDS, 16B per lane; dest must be wave-uniform base (+lane*16 by HW)
#define GLL16(g, l) \
    __builtin_amdgcn_global_load_lds((const __attribute__((address_space(1))) unsigned int*)(g), \
                                     (__attribute__((address_space(3))) unsigned int*)(l), 16, 0, 0)

// ---------------- fused routing: histogram + offsets + scatter + XCD-grouped block tables ----------------
// single block, 256 threads
__global__ void route_all_k(const int* __restrict__ idx,
                            const float* __restrict__ wts,
                            int* __restrict__ counts_g,
                            int* __restrict__ btok,
                            float* __restrict__ bw,
                            int* __restrict__ offs_g,
                            int* __restrict__ slotmap,
                            int* __restrict__ gu_tab,
                            int* __restrict__ dn_tab) {
    __shared__ int h[NEXP], nt[NEXP], pre[NEXP], base[NEXP], cur[NEXP];
    const int tid = threadIdx.x;
    if (tid < NEXP) { h[tid] = 0; cur[tid] = 0; }
    __syncthreads();
    for (int s = tid; s < NSLOT; s += 256) atomicAdd(&h[idx[s]], 1);
    __syncthreads();
    if (tid == 0) {
        int a = 0;
        for (int e = 0; e < NEXP; ++e) {
            base[e] = a; counts_g[e] = h[e]; offs_g[e] = a;
            int t = (h[e] + 127) >> 7; nt[e] = t; a += t << 7;
        }
        int p = 0;
        for (int e = 0; e < NEXP; ++e) { pre[e] = p; p += nt[e]; }
    }
    __syncthreads();
    for (int s = tid; s < NSLOT; s += 256) {
        int e = idx[s];
        int p = atomicAdd(&cur[e], 1);
        btok[e * NSLOT + p] = s >> 1;          // token id (TOPK=2)
        bw[e * NSLOT + p] = wts[s];
        slotmap[s] = base[e] + p;              // global compact row
    }
    for (int i = tid; i < 8 * SLOTS; i += 256) { gu_tab[i] = -1; dn_tab[i] = -1; }
    __syncthreads();
    if (tid < 128) {
        int c = tid, e = c >> 4, ib = c & 15;
        int sb = 2 * pre[e] + (ib >> 3) * nt[e];
        for (int j = 0; j < nt[e]; ++j)
            gu_tab[(sb + j) * 8 + (ib & 7)] = (e << 16) | (ib << 8) | j;
    } else {
        int c = tid - 128, e = c >> 4, ib = c & 15;
        int sb = 2 * pre[e] + (ib >> 3) * nt[e];
        for (int j = 0; j < nt[e]; ++j)
            dn_tab[(sb + j) * 8 + (ib & 7)] = (e << 16) | (ib << 8) | j;
    }
}

// ---------------- fp32 -> bf16 conversion kernels (8 elems/thread) ----------------
__device__ __forceinline__ void cvt8(const float* __restrict__ src,
                                     unsigned short* __restrict__ dst, size_t o) {
    const float4* s4 = (const float4*)src + o * 2;
    float4 a = s4[0], b = s4[1];
    union { unsigned short s[8]; uint4 v; } r;
    r.s[0] = f2bf(a.x); r.s[1] = f2bf(a.y); r.s[2] = f2bf(a.z); r.s[3] = f2bf(a.w);
    r.s[4] = f2bf(b.x); r.s[5] = f2bf(b.y); r.s[6] = f2bf(b.z); r.s[7] = f2bf(b.w);
    ((uint4*)dst)[o] = r.v;
}

// segments: x (NTOK*HID), gate (NEXP*ITR*HID), up (NEXP*ITR*HID)
__global__ void cvt_gux_k(const float* __restrict__ x, const float* __restrict__ g,
                          const float* __restrict__ u,
                          unsigned short* __restrict__ xb, unsigned short* __restrict__ gb,
                          unsigned short* __restrict__ ub) {
    size_t j = (size_t)blockIdx.x * 256 + threadIdx.x;
    const size_t X8 = (size_t)NTOK * HID / 8;
    const size_t W8 = (size_t)NEXP * ITR * HID / 8;
    if (j < X8)           cvt8(x, xb, j);
    else if (j < X8 + W8) cvt8(g, gb, j - X8);
    else                  cvt8(u, ub, j - X8 - W8);
}

__global__ void cvt_dn_k(const float* __restrict__ d, unsigned short* __restrict__ db) {
    size_t j = (size_t)blockIdx.x * 256 + threadIdx.x;
    cvt8(d, db, j);
}

// combine: out[t] = part[slot0[t]] + part[slot1[t]]  (weights already applied)
__global__ void combine_k(const float* __restrict__ part,
                          const int* __restrict__ slotmap,
                          float* __restrict__ out) {
    int gid = blockIdx.x * 256 + threadIdx.x;
    int t = gid >> 9;
    int c = gid & 511;
    int s0 = slotmap[t * 2], s1 = slotmap[t * 2 + 1];
    float4 a = ((const float4*)part)[(size_t)s0 * 512 + c];
    float4 b = ((const float4*)part)[(size_t)s1 * 512 + c];
    float4 r; r.x = a.x + b.x; r.y = a.y + b.y; r.z = a.z + b.z; r.w = a.w + b.w;
    ((float4*)out)[gid] = r;
}

// ================= bf16 MFMA path with global_load_lds (new) =================
#define BK 64

// Stage 1: M=128 slots x N=64 inter cols (gate & up), K=2048. grid = 8*SLOTS via gu_tab
// Linear LDS dest (global_load_lds), XOR-swizzled source + matching XOR on ds_read.
__launch_bounds__(256)
__global__ void moe_gu_bf_k(const unsigned short* __restrict__ xb,
                            const unsigned short* __restrict__ gateb,
                            const unsigned short* __restrict__ upb,
                            const int* __restrict__ counts,
                            const int* __restrict__ btok,
                            const int* __restrict__ off,
                            const int* __restrict__ gu_tab,
                            unsigned short* __restrict__ interw) {
    const int v = gu_tab[blockIdx.x];
    if (v < 0) return;
    const int e    = v >> 16;
    const int iblk = (v >> 8) & 255;
    const int tile = v & 255;
    const int n = counts[e];

    __shared__ unsigned short s_a[128 * 64];   // [row][64 bf16], 128B rows, XOR-swizzled
    __shared__ unsigned short s_bg[64 * 64];
    __shared__ unsigned short s_bu[64 * 64];
    __shared__ int s_tok[128];

    const int tid = threadIdx.x;
    if (tid < 128) {
        int tt = tile * 128 + tid;
        s_tok[tid] = btok[e * NSLOT + (tt < n ? tt : n - 1)];
    }
    __syncthreads();

    const int w = tid >> 6;
    const int lane = tid & 63;

    // A staging: 4 insts x 256 threads x 16B = 128 rows x 128B
    const char* asrc[4]; unsigned short* adst[4];
    #pragma unroll
    for (int t = 0; t < 4; ++t) {
        int c = tid + t * 256;
        int r = c >> 3;
        unsigned sw = ((unsigned)(c & 7) * 16u) ^ (((unsigned)r & 7u) << 4);
        asrc[t] = (const char*)xb + (size_t)s_tok[r] * (HID * 2) + sw;
        adst[t] = s_a + (size_t)(t * 256 + w * 64) * 8;   // wave-uniform base
    }
    // B staging: 2 insts each for gate/up = 64 rows x 128B each
    const char* gB = (const char*)gateb + ((size_t)e * ITR + (size_t)iblk * 64) * (HID * 2);
    const char* uB = (const char*)upb   + ((size_t)e * ITR + (size_t)iblk * 64) * (HID * 2);
    const char* gsrc[2]; const char* usrc[2];
    unsigned short* gdst[2]; unsigned short* udst[2];
    #pragma unroll
    for (int t = 0; t < 2; ++t) {
        int c = tid + t * 256;
        int r = c >> 3;
        unsigned sw = ((unsigned)(c & 7) * 16u) ^ (((unsigned)r & 7u) << 4);
        gsrc[t] = gB + (size_t)r * (HID * 2) + sw;
        usrc[t] = uB + (size_t)r * (HID * 2) + sw;
        gdst[t] = s_bg + (size_t)(t * 256 + w * 64) * 8;
        udst[t] = s_bu + (size_t)(t * 256 + w * 64) * 8;
    }

    const int wm = (w & 1) * 64, wn = (w >> 1) * 32;
    const int l15 = lane & 15, quad = lane >> 4;

    f32x4 accg[4][2], accu[4][2];
    #pragma unroll
    for (int m = 0; m < 4; ++m)
        #pragma unroll
        for (int nn = 0; nn < 2; ++nn) {
            accg[m][nn] = (f32x4){0.f, 0.f, 0.f, 0.f};
            accu[m][nn] = (f32x4){0.f, 0.f, 0.f, 0.f};
        }

    for (int k0 = 0; k0 < HID; k0 += BK) {
        const int kb0 = k0 * 2;
        #pragma unroll
        for (int t = 0; t < 4; ++t) GLL16(asrc[t] + kb0, adst[t]);
        #pragma unroll
        for (int t = 0; t < 2; ++t) { GLL16(gsrc[t] + kb0, gdst[t]); GLL16(usrc[t] + kb0, udst[t]); }
        __syncthreads();   // drains vmcnt(0): LDS tile ready
        #pragma unroll
        for (int kk = 0; kk < 2; ++kk) {
            const unsigned kbyte = (unsigned)(kk * 64 + quad * 16);
            short8 af[4], bg[2], bu[2];
            #pragma unroll
            for (int m = 0; m < 4; ++m) {
                unsigned r = (unsigned)(wm + m * 16 + l15);
                af[m] = *(const short8*)&s_a[r * 64 + ((kbyte ^ ((r & 7u) << 4)) >> 1)];
            }
            #pragma unroll
            for (int nn = 0; nn < 2; ++nn) {
                unsigned r = (unsigned)(wn + nn * 16 + l15);
                unsigned co = (kbyte ^ ((r & 7u) << 4)) >> 1;
                bg[nn] = *(const short8*)&s_bg[r * 64 + co];
                bu[nn] = *(const short8*)&s_bu[r * 64 + co];
            }
            #pragma unroll
            for (int m = 0; m < 4; ++m)
                #pragma unroll
                for (int nn = 0; nn < 2; ++nn) {
                    accg[m][nn] = __builtin_amdgcn_mfma_f32_16x16x32_bf16(af[m], bg[nn], accg[m][nn], 0, 0, 0);
                    accu[m][nn] = __builtin_amdgcn_mfma_f32_16x16x32_bf16(af[m], bu[nn], accu[m][nn], 0, 0, 0);
                }
        }
        __syncthreads();
    }

    const int pos0 = off[e] + tile * 128;
    #pragma unroll
    for (int m = 0; m < 4; ++m) {
        #pragma unroll
        for (int nn = 0; nn < 2; ++nn) {
            int col = iblk * 64 + wn + nn * 16 + l15;
            #pragma unroll
            for (int r = 0; r < 4; ++r) {
                int row = wm + m * 16 + quad * 4 + r;
                float g = accg[m][nn][r], u = accu[m][nn][r];
                float s = g / (1.0f + __expf(-g));
                interw[(size_t)(pos0 + row) * ITR + col] = f2bf(s * u);
            }
        }
    }
}

// Stage 2: M=128 slots x N=128 hid cols, K=1024. grid = 8*SLOTS via dn_tab
__launch_bounds__(256)
__global__ void moe_down_bf_k(const unsigned short* __restrict__ interw,
                              const unsigned short* __restrict__ downb,
                              const int* __restrict__ counts,
                              const int* __restrict__ btok,
                              const float* __restrict__ bw,
                              const int* __restrict__ off,
                              const int* __restrict__ dn_tab,
                              float* __restrict__ dst,
                              int mode) {
    const int v = dn_tab[blockIdx.x];
    if (v < 0) return;
    const int e    = v >> 16;
    const int hblk = (v >> 8) & 255;
    const int tile = v & 255;
    const int n = counts[e];

    __shared__ unsigned short s_a[128 * 64];
    __shared__ unsigned short s_b[128 * 64];
    __shared__ int s_tok[128];
    __shared__ float s_w[128];

    const int tid = threadIdx.x;
    if (tid < 128) {
        int tt = tile * 128 + tid;
        bool vv = tt < n;
        s_tok[tid] = btok[e * NSLOT + (vv ? tt : n - 1)];
        s_w[tid] = vv ? bw[e * NSLOT + tt] : 0.0f;
    }
    __syncthreads();

    const int w = tid >> 6;
    const int lane = tid & 63;
    const int pos0 = off[e] + tile * 128;

    const char* asrc[4]; unsigned short* adst[4];
    const char* bsrc[4]; unsigned short* bdst[4];
    const char* dB = (const char*)downb + ((size_t)e * HID + (size_t)hblk * 128) * (ITR * 2);
    #pragma unroll
    for (int t = 0; t < 4; ++t) {
        int c = tid + t * 256;
        int r = c >> 3;
        unsigned sw = ((unsigned)(c & 7) * 16u) ^ (((unsigned)r & 7u) << 4);
        asrc[t] = (const char*)interw + (size_t)(pos0 + r) * (ITR * 2) + sw;
        bsrc[t] = dB + (size_t)r * (ITR * 2) + sw;
        adst[t] = s_a + (size_t)(t * 256 + w * 64) * 8;
        bdst[t] = s_b + (size_t)(t * 256 + w * 64) * 8;
    }

    const int wm = (w & 1) * 64, wn = (w >> 1) * 64;
    const int l15 = lane & 15, quad = lane >> 4;

    f32x4 acc[4][4];
    #pragma unroll
    for (int m = 0; m < 4; ++m)
        #pragma unroll
        for (int nn = 0; nn < 4; ++nn) acc[m][nn] = (f32x4){0.f, 0.f, 0.f, 0.f};

    for (int k0 = 0; k0 < ITR; k0 += BK) {
        const int kb0 = k0 * 2;
        #pragma unroll
        for (int t = 0; t < 4; ++t) GLL16(asrc[t] + kb0, adst[t]);
        #pragma unroll
        for (int t = 0; t < 4; ++t) GLL16(bsrc[t] + kb0, bdst[t]);
        __syncthreads();
        #pragma unroll
        for (int kk = 0; kk < 2; ++kk) {
            const unsigned kbyte = (unsigned)(kk * 64 + quad * 16);
            short8 af[4], bf[4];
            #pragma unroll
            for (int m = 0; m < 4; ++m) {
                unsigned r = (unsigned)(wm + m * 16 + l15);
                af[m] = *(const short8*)&s_a[r * 64 + ((kbyte ^ ((r & 7u) << 4)) >> 1)];
            }
            #pragma unroll
            for (int nn = 0; nn < 4; ++nn) {
                unsigned r = (unsigned)(wn + nn * 16 + l15);
                bf[nn] = *(const short8*)&s_b[r * 64 + ((kbyte ^ ((r & 7u) << 4)) >> 1)];
            }
            #pragma unroll
            for (int m = 0; m < 4; ++m)
                #pragma unroll
                for (int nn = 0; nn < 4; ++nn)
                    acc[m][nn] = __builtin_amdgcn_mfma_f32_16x16x32_bf16(af[m], bf[nn], acc[m][nn], 0, 0, 0);
        }
        __syncthreads();
    }

    if (mode == 0) {
        #pragma unroll
        for (int m = 0; m < 4; ++m) {
            #pragma unroll
            for (int nn = 0; nn < 4; ++nn) {
                int col = hblk * 128 + wn + nn * 16 + l15;
                #pragma unroll
                for (int r = 0; r < 4; ++r) {
                    int row = wm + m * 16 + quad * 4 + r;
                    dst[(size_t)(pos0 + row) * HID + col] = s_w[row] * acc[m][nn][r];
                }
            }
        }
    } else {
        #pragma unroll
        for (int m = 0; m < 4; ++m) {
            #pragma unroll
            for (int nn = 0; nn < 4; ++nn) {
                int col = hblk * 128 + wn + nn * 16 + l15;
                #pragma unroll
                for (int r = 0; r < 4; ++r) {
                    int row = wm + m * 16 + quad * 4 + r;
                    atomicAdd(&dst[(size_t)s_tok[row] * HID + col], s_w[row] * acc[m][nn][r]);
                }
            }
        }
    }
}

// ================= legacy MFMA path (fallback when ws too small for bf16 weights) =================
#define LDW 72

__global__ void xconv_k(const float* __restrict__ x, unsigned short* __restrict__ xb) {
    int i = blockIdx.x * blockDim.x + threadIdx.x;
    float4 v = ((const float4*)x)[i];
    ushort4 b;
    b.x = f2bf(v.x); b.y = f2bf(v.y); b.z = f2bf(v.z); b.w = f2bf(v.w);
    ((ushort4*)xb)[i] = b;
}

__launch_bounds__(256)
__global__ void moe_gu_k(const unsigned short* __restrict__ xb,
                         const float* __restrict__ gate,
                         const float* __restrict__ up,
                         const int* __restrict__ counts,
                         const int* __restrict__ btok,
                         const int* __restrict__ off,
                         const int* __restrict__ gu_tab,
                         unsigned short* __restrict__ interw) {
    const int v = gu_tab[blockIdx.x];
    if (v < 0) return;
    const int e    = v >> 16;
    const int iblk = (v >> 8) & 255;
    const int tile = v & 255;
    const int n = counts[e];

    __shared__ unsigned short s_a[128][LDW];
    __shared__ unsigned short s_bg[64][LDW];
    __shared__ unsigned short s_bu[64][LDW];
    __shared__ int s_tok[128];

    const int tid = threadIdx.x;
    if (tid < 128) {
        int tt = tile * 128 + tid;
        s_tok[tid] = btok[e * NSLOT + (tt < n ? tt : n - 1)];
    }
    __syncthreads();

    const unsigned short* asrc[4];
    unsigned aoff[4];
    #pragma unroll
    for (int t = 0; t < 4; ++t) {
        int c = tid + t * 256;
        int r = c >> 3, col = (c & 7) * 8;
        asrc[t] = xb + (size_t)s_tok[r] * HID + col;
        aoff[t] = r * LDW + col;
    }
    const float* gbase = gate + (size_t)e * ITR * HID + (size_t)iblk * 64 * HID;
    const float* ubase = up   + (size_t)e * ITR * HID + (size_t)iblk * 64 * HID;
    unsigned boff[4], loff[4];
    #pragma unroll
    for (int t = 0; t < 4; ++t) {
        int f = tid + t * 256;
        int r = f >> 4, col = (f & 15) * 4;
        boff[t] = r * HID + col;
        loff[t] = r * LDW + col;
    }

    const int lane = tid & 63;
    const int w = tid >> 6;
    const int wm = (w & 1) * 64, wn = (w >> 1) * 32;
    const int l15 = lane & 15, quad = lane >> 4;

    f32x4 accg[4][2], accu[4][2];
    #pragma unroll
    for (int m = 0; m < 4; ++m)
        #pragma unroll
        for (int nn = 0; nn < 2; ++nn) {
            accg[m][nn] = (f32x4){0.f, 0.f, 0.f, 0.f};
            accu[m][nn] = (f32x4){0.f, 0.f, 0.f, 0.f};
        }

    unsigned short* s_flat_a = &s_a[0][0];
    unsigned short* s_flat_g = &s_bg[0][0];
    unsigned short* s_flat_u = &s_bu[0][0];

    uint4 pa[4];
    float4 pg[4], pu[4];
    #pragma unroll
    for (int t = 0; t < 4; ++t) {
        pa[t] = *(const uint4*)(asrc[t]);
        pg[t] = *(const float4*)(gbase + boff[t]);
        pu[t] = *(const float4*)(ubase + boff[t]);
    }

    for (int k0 = 0; k0 < HID; k0 += BK) {
        #pragma unroll
        for (int t = 0; t < 4; ++t) {
            *(uint4*)(s_flat_a + aoff[t]) = pa[t];
            ushort4 gb, ub;
            gb.x = f2bf(pg[t].x); gb.y = f2bf(pg[t].y); gb.z = f2bf(pg[t].z); gb.w = f2bf(pg[t].w);
            ub.x = f2bf(pu[t].x); ub.y = f2bf(pu[t].y); ub.z = f2bf(pu[t].z); ub.w = f2bf(pu[t].w);
            *(ushort4*)(s_flat_g + loff[t]) = gb;
            *(ushort4*)(s_flat_u + loff[t]) = ub;
        }
        __syncthreads();
        if (k0 + BK < HID) {
            #pragma unroll
            for (int t = 0; t < 4; ++t) {
                pa[t] = *(const uint4*)(asrc[t] + k0 + BK);
                pg[t] = *(const float4*)(gbase + boff[t] + k0 + BK);
                pu[t] = *(const float4*)(ubase + boff[t] + k0 + BK);
            }
        }
        #pragma unroll
        for (int kk = 0; kk < 2; ++kk) {
            const int kc = kk * 32 + quad * 8;
            short8 af[4], bg[2], bu[2];
            #pragma unroll
            for (int m = 0; m < 4; ++m)
                af[m] = *(const short8*)&s_a[wm + m * 16 + l15][kc];
            #pragma unroll
            for (int nn = 0; nn < 2; ++nn) {
                bg[nn] = *(const short8*)&s_bg[wn + nn * 16 + l15][kc];
                bu[nn] = *(const short8*)&s_bu[wn + nn * 16 + l15][kc];
            }
            #pragma unroll
            for (int m = 0; m < 4; ++m)
                #pragma unroll
                for (int nn = 0; nn < 2; ++nn) {
                    accg[m][nn] = __builtin_amdgcn_mfma_f32_16x16x32_bf16(af[m], bg[nn], accg[m][nn], 0, 0, 0);
                    accu[m][nn] = __builtin_amdgcn_mfma_f32_16x16x32_bf16(af[m], bu[nn], accu[m][nn], 0, 0, 0);
                }
        }
        __syncthreads();
    }

    const int pos0 = off[e] + tile * 128;
    #pragma unroll
    for (int m = 0; m < 4; ++m) {
        #pragma unroll
        for (int nn = 0; nn < 2; ++nn) {
            int col = iblk * 64 + wn + nn * 16 + l15;
            #pragma unroll
            for (int r = 0; r < 4; ++r) {
                int row = wm + m * 16 + quad * 4 + r;
                float g = accg[m][nn][r], u = accu[m][nn][r];
                float s = g / (1.0f + __expf(-g));
                interw[(size_t)(pos0 + row) * ITR + col] = f2bf(s * u);
            }
        }
    }
}

__launch_bounds__(256)
__global__ void moe_down_k(const unsigned short* __restrict__ interw,
                           const float* __restrict__ down,
                           const int* __restrict__ counts,
                           const int* __restrict__ btok,
                           const float* __restrict__ bw,
                           const int* __restrict__ off,
                           const int* __restrict__ dn_tab,
                           float* __restrict__ dst,
                           int mode) {
    const int v = dn_tab[blockIdx.x];
    if (v < 0) return;
    const int e    = v >> 16;
    const int hblk = (v >> 8) & 255;
    const int tile = v & 255;
    const int n = counts[e];

    __shared__ unsigned short s_a[128][LDW];
    __shared__ unsigned short s_b[128][LDW];
    __shared__ int s_tok[128];
    __shared__ float s_w[128];

    const int tid = threadIdx.x;
    if (tid < 128) {
        int tt = tile * 128 + tid;
        bool vv = tt < n;
        s_tok[tid] = btok[e * NSLOT + (vv ? tt : n - 1)];
        s_w[tid] = vv ? bw[e * NSLOT + tt] : 0.0f;
    }
    __syncthreads();

    const int pos0 = off[e] + tile * 128;
    unsigned aoff[4], asrco[4];
    #pragma unroll
    for (int t = 0; t < 4; ++t) {
        int c = tid + t * 256;
        int r = c >> 3, col = (c & 7) * 8;
        asrco[t] = (unsigned)((pos0 + r) * ITR + col);
        aoff[t] = r * LDW + col;
    }
    const float* dbase = down + (size_t)e * HID * ITR + (size_t)hblk * 128 * ITR;
    unsigned boff[8], loff[8];
    #pragma unroll
    for (int t = 0; t < 8; ++t) {
        int f = tid + t * 256;
        int r = f >> 4, col = (f & 15) * 4;
        boff[t] = r * ITR + col;
        loff[t] = r * LDW + col;
    }

    const int lane = tid & 63;
    const int w = tid >> 6;
    const int wm = (w & 1) * 64, wn = (w >> 1) * 64;
    const int l15 = lane & 15, quad = lane >> 4;

    f32x4 acc[4][4];
    #pragma unroll
    for (int m = 0; m < 4; ++m)
        #pragma unroll
        for (int nn = 0; nn < 4; ++nn) acc[m][nn] = (f32x4){0.f, 0.f, 0.f, 0.f};

    unsigned short* s_flat_a = &s_a[0][0];
    unsigned short* s_flat_b = &s_b[0][0];

    uint4 pa[4];
    float4 pb[8];
    #pragma unroll
    for (int t = 0; t < 4; ++t) pa[t] = *(const uint4*)(interw + asrco[t]);
    #pragma unroll
    for (int t = 0; t < 8; ++t) pb[t] = *(const float4*)(dbase + boff[t]);

    for (int k0 = 0; k0 < ITR; k0 += BK) {
        #pragma unroll
        for (int t = 0; t < 4; ++t)
            *(uint4*)(s_flat_a + aoff[t]) = pa[t];
        #pragma unroll
        for (int t = 0; t < 8; ++t) {
            ushort4 b;
            b.x = f2bf(pb[t].x); b.y = f2bf(pb[t].y); b.z = f2bf(pb[t].z); b.w = f2bf(pb[t].w);
            *(ushort4*)(s_flat_b + loff[t]) = b;
        }
        __syncthreads();
        if (k0 + BK < ITR) {
            #pragma unroll
            for (int t = 0; t < 4; ++t) pa[t] = *(const uint4*)(interw + asrco[t] + k0 + BK);
            #pragma unroll
            for (int t = 0; t < 8; ++t) pb[t] = *(const float4*)(dbase + boff[t] + k0 + BK);
        }
        #pragma unroll
        for (int kk = 0; kk < 2; ++kk) {
            const int kc = kk * 32 + quad * 8;
            short8 af[4], bf[4];
            #pragma unroll
            for (int m = 0; m < 4; ++m)
                af[m] = *(const short8*)&s_a[wm + m * 16 + l15][kc];
            #pragma unroll
            for (int nn = 0; nn < 4; ++nn)
                bf[nn] = *(const short8*)&s_b[wn + nn * 16 + l15][kc];
            #pragma unroll
            for (int m = 0; m < 4; ++m)
                #pragma unroll
                for (int nn = 0; nn < 4; ++nn)
                    acc[m][nn] = __builtin_amdgcn_mfma_f32_16x16x32_bf16(af[m], bf[nn], acc[m][nn], 0, 0, 0);
        }
        __syncthreads();
    }

    if (mode == 0) {
        #pragma unroll
        for (int m = 0; m < 4; ++m) {
            #pragma unroll
            for (int nn = 0; nn < 4; ++nn) {
                int col = hblk * 128 + wn + nn * 16 + l15;
                #pragma unroll
                for (int r = 0; r < 4; ++r) {
                    int row = wm + m * 16 + quad * 4 + r;
                    dst[(size_t)(pos0 + row) * HID + col] = s_w[row] * acc[m][nn][r];
                }
            }
        }
    } else {
        #pragma unroll
        for (int m = 0; m < 4; ++m) {
            #pragma unroll
            for (int nn = 0; nn < 4; ++nn) {
                int col = hblk * 128 + wn + nn * 16 + l15;
                #pragma unroll
                for (int r = 0; r < 4; ++r) {
                    int row = wm + m * 16 + quad * 4 + r;
                    atomicAdd(&dst[(size_t)s_tok[row] * HID + col], s_w[row] * acc[m][nn][r]);
                }
            }
        }
    }
}

// ================= fp32 fallback (used only if ws too small) =================
#define TT 8
#define TN 128
#define TK 16
#define WPAD 20
#define IPAD 1028
#define MAXTILES (NSLOT / TT)

__global__ void route_k(const int* __restrict__ idx,
                        const float* __restrict__ wts,
                        int* __restrict__ counts,
                        int* __restrict__ btok,
                        float* __restrict__ bw) {
    int s = blockIdx.x * blockDim.x + threadIdx.x;
    if (s >= NSLOT) return;
    int e = idx[s];
    int pos = atomicAdd(&counts[e], 1);
    btok[(size_t)e * NSLOT + pos] = s / TOPK;
    bw[(size_t)e * NSLOT + pos] = wts[s];
}

__launch_bounds__(256)
__global__ void moe_k(const float* __restrict__ x,
                      const float* __restrict__ gate,
                      const float* __restrict__ up,
                      const float* __restrict__ down,
                      const int* __restrict__ counts,
                      const int* __restrict__ btok,
                      const float* __restrict__ bw,
                      float* __restrict__ out) {
    const int e = blockIdx.x / MAXTILES;
    const int tile = blockIdx.x % MAXTILES;
    const int n = counts[e];
    const int t0 = tile * TT;
    if (t0 >= n) return;

    __shared__ float s_wg[TN][WPAD];
    __shared__ float s_wu[TN][WPAD];
    __shared__ float s_it[TT][IPAD];
    __shared__ int   s_tok[TT];
    __shared__ float s_w[TT];

    const int tid = threadIdx.x;
    if (tid < TT) {
        int tt = t0 + tid;
        bool v = tt < n;
        s_tok[tid] = btok[(size_t)e * NSLOT + (v ? tt : t0)];
        s_w[tid] = v ? bw[(size_t)e * NSLOT + tt] : 0.0f;
    }
    __syncthreads();

    const int tok = tid >> 5;
    const int ic  = (tid & 31) << 2;
    const int mytok = s_tok[tok];
    const float* xrow = x + (size_t)mytok * HID;
    const float* gbase = gate + (size_t)e * ITR * HID;
    const float* ubase = up   + (size_t)e * ITR * HID;
    const float* dbase = down + (size_t)e * HID * ITR;

    for (int i0 = 0; i0 < ITR; i0 += TN) {
        float ag[4] = {0.f, 0.f, 0.f, 0.f};
        float au[4] = {0.f, 0.f, 0.f, 0.f};
        for (int k0 = 0; k0 < HID; k0 += TK) {
            #pragma unroll
            for (int j = 0; j < 2; ++j) {
                int f4 = tid + j * 256;
                int r = f4 >> 2, c = (f4 & 3) << 2;
                *(float4*)&s_wg[r][c] = *(const float4*)(gbase + (size_t)(i0 + r) * HID + k0 + c);
                *(float4*)&s_wu[r][c] = *(const float4*)(ubase + (size_t)(i0 + r) * HID + k0 + c);
            }
            __syncthreads();
            #pragma unroll
            for (int kk = 0; kk < TK; kk += 4) {
                float4 xv = *(const float4*)(xrow + k0 + kk);
                #pragma unroll
                for (int q = 0; q < 4; ++q) {
                    float4 wg = *(const float4*)&s_wg[ic + q][kk];
                    float4 wu = *(const float4*)&s_wu[ic + q][kk];
                    ag[q] += xv.x * wg.x + xv.y * wg.y + xv.z * wg.z + xv.w * wg.w;
                    au[q] += xv.x * wu.x + xv.y * wu.y + xv.z * wu.z + xv.w * wu.w;
                }
            }
            __syncthreads();
        }
        #pragma unroll
        for (int q = 0; q < 4; ++q) {
            float g = ag[q], u = au[q];
            s_it[tok][i0 + ic + q] = (g / (1.0f + __expf(-g))) * u;
        }
    }
    __syncthreads();

    const float wscale = s_w[tok];
    for (int h0 = 0; h0 < HID; h0 += TN) {
        float ac[4] = {0.f, 0.f, 0.f, 0.f};
        for (int k0 = 0; k0 < ITR; k0 += TK) {
            #pragma unroll
            for (int j = 0; j < 2; ++j) {
                int f4 = tid + j * 256;
                int r = f4 >> 2, c = (f4 & 3) << 2;
                *(float4*)&s_wg[r][c] = *(const float4*)(dbase + (size_t)(h0 + r) * ITR + k0 + c);
            }
            __syncthreads();
            #pragma unroll
            for (int kk = 0; kk < TK; kk += 4) {
                float4 xv = *(const float4*)&s_it[tok][k0 + kk];
                #pragma unroll
                for (int q = 0; q < 4; ++q) {
                    float4 wv = *(const float4*)&s_wg[ic + q][kk];
                    ac[q] += xv.x * wv.x + xv.y * wv.y + xv.z * wv.z + xv.w * wv.w;
                }
            }
            __syncthreads();
        }
        float* orow = out + (size_t)mytok * HID + h0 + ic;
        #pragma unroll
        for (int q = 0; q < 4; ++q) atomicAdd(&orow[q], wscale * ac[q]);
    }
}

extern "C" void kernel_launch(void* const* d_in, const int* in_sizes, int n_in,
                              void* d_out, int out_size, void* d_ws, size_t ws_size,
                              hipStream_t stream) {
    const float* x    = (const float*)d_in[0];
    const int*   idx  = (const int*)d_in[1];
    const float* wts  = (const float*)d_in[2];
    const float* gate = (const float*)d_in[3];
    const float* up   = (const float*)d_in[4];
    const float* down = (const float*)d_in[5];
    float* out = (float*)d_out;

    // ---- common small region ----
    const size_t off_btok  = 256;
    const size_t off_bw    = off_btok + (size_t)NEXP * NSLOT * 4;      // 128 KB
    const size_t off_offs  = off_bw + (size_t)NEXP * NSLOT * 4;        // 128 KB
    const size_t off_smap  = off_offs + 256;
    const size_t off_tabs  = off_smap + (size_t)NSLOT * 4;             // 16 KB
    const size_t off_xb    = off_tabs + 2 * 8 * SLOTS * 4;             // 5.1 KB

    // ---- legacy layout (fallback tiers) ----
    const size_t off_inter_o = off_xb + (size_t)NTOK * HID * 2;            // 8 MB
    const size_t off_part_o  = off_inter_o + (size_t)(MAXTT * 128) * ITR * 2;  // 10.5 MB
    const size_t need_mid  = off_part_o;
    const size_t need_full = off_part_o + (size_t)(MAXTT * 128) * HID * 4;     // +42 MB

    // ---- new bf16-weight layout (liveness-aliased) ----
    // Live sets: cvt1 {xb,gb,ub} -> gu {xb,gb,ub -> interw} -> cvt2 {db over xb/gb-head}
    //            -> down {interw,db -> part over gb-tail/ub} -> combine {part -> out}
    const size_t XBSZ  = (size_t)NTOK * HID * 2;          //  8.39 MB
    const size_t WSZ   = (size_t)NEXP * ITR * HID * 2;    // 33.55 MB each
    const size_t INTSZ = (size_t)(MAXTT * 128) * ITR * 2; // 10.49 MB
    const size_t off_gb      = off_xb + XBSZ;
    const size_t off_ub      = off_gb + WSZ;
    const size_t off_inter_n = off_ub + WSZ;
    const size_t off_db      = off_xb;                    // aliases xb + gb head (dead after gu)
    const size_t off_part_n  = off_db + WSZ;              // aliases gb tail + ub (dead after gu)
    const size_t need_bf     = off_inter_n + INTSZ;       // ~86.3 MB total
    // part end = off_xb + WSZ + 40*128*2048*4 = off_xb + 75,497,472 == off_inter_n  (exact fit)

    int*   counts = (int*)d_ws;
    int*   btok   = (int*)((char*)d_ws + off_btok);
    float* bwp    = (float*)((char*)d_ws + off_bw);
    int*   offs   = (int*)((char*)d_ws + off_offs);
    int*   smap   = (int*)((char*)d_ws + off_smap);
    int*   gu_tab = (int*)((char*)d_ws + off_tabs);
    int*   dn_tab = gu_tab + 8 * SLOTS;
    unsigned short* xb = (unsigned short*)((char*)d_ws + off_xb);

    if (ws_size >= need_bf) {
        unsigned short* gb     = (unsigned short*)((char*)d_ws + off_gb);
        unsigned short* ub     = (unsigned short*)((char*)d_ws + off_ub);
        unsigned short* db     = (unsigned short*)((char*)d_ws + off_db);
        unsigned short* interw = (unsigned short*)((char*)d_ws + off_inter_n);
        float*          part   = (float*)((char*)d_ws + off_part_n);

        const int cvt1_blocks = (int)(((size_t)NTOK * HID / 8 + 2 * (WSZ / 16)) / 256); // 18432
        const int cvt2_blocks = (int)((WSZ / 16) / 256);                                 // 8192

        route_all_k<<<dim3(1), dim3(256), 0, stream>>>(idx, wts, counts, btok, bwp, offs, smap, gu_tab, dn_tab);
        cvt_gux_k<<<dim3(cvt1_blocks), dim3(256), 0, stream>>>(x, gate, up, xb, gb, ub);
        moe_gu_bf_k<<<dim3(8 * SLOTS), dim3(256), 0, stream>>>(xb, gb, ub, counts, btok, offs, gu_tab, interw);
        cvt_dn_k<<<dim3(cvt2_blocks), dim3(256), 0, stream>>>(down, db);
        moe_down_bf_k<<<dim3(8 * SLOTS), dim3(256), 0, stream>>>(interw, db, counts, btok, bwp, offs, dn_tab, part, 0);
        combine_k<<<dim3(NTOK * HID / 4 / 256), dim3(256), 0, stream>>>(part, smap, out);
    } else if (ws_size >= need_mid) {
        const int full = (ws_size >= need_full);
        unsigned short* interw = (unsigned short*)((char*)d_ws + off_inter_o);
        float* part   = (float*)((char*)d_ws + off_part_o);
        route_all_k<<<dim3(1), dim3(256), 0, stream>>>(idx, wts, counts, btok, bwp, offs, smap, gu_tab, dn_tab);
        xconv_k<<<dim3(NTOK * HID / 4 / 256), dim3(256), 0, stream>>>(x, xb);
        if (!full) hipMemsetAsync(d_out, 0, (size_t)out_size * sizeof(float), stream);
        moe_gu_k<<<dim3(8 * SLOTS), dim3(256), 0, stream>>>(xb, gate, up, counts, btok, offs, gu_tab, interw);
        moe_down_k<<<dim3(8 * SLOTS), dim3(256), 0, stream>>>(interw, down, counts, btok, bwp, offs, dn_tab,
                                                              full ? part : out, full ? 0 : 1);
        if (full)
            combine_k<<<dim3(NTOK * HID / 4 / 256), dim3(256), 0, stream>>>(part, smap, out);
    } else {
        hipMemsetAsync(d_out, 0, (size_t)out_size * sizeof(float), stream);
        hipMemsetAsync(counts, 0, 256, stream);
        route_k<<<dim3((NSLOT + 255) / 256), dim3(256), 0, stream>>>(idx, wts, counts, btok, bwp);
        moe_k<<<dim3(NEXP * MAXTILES), dim3(256), 0, stream>>>(x, gate, up, down, counts, btok, bwp, out);
    }
}

// Round 2
// 353.463 us; speedup vs baseline: 1.2460x; 1.0200x over previous
//
#include <hip/hip_runtime.h>
#include <math.h>

#define HID 2048
#define ITR 1024
#define NEXP 8
#define TOPK 2
#define NTOK 2048
#define NSLOT (NTOK * TOPK)
#define MAXTT 40        // max 128-row tiles across experts (bound 4096/128+7=39)
#define SLOTS 80        // per-XCD slot count for block tables (bound 2*39=78)

typedef __attribute__((ext_vector_type(8))) short short8;
typedef __attribute__((ext_vector_type(4))) float f32x4;

__device__ __forceinline__ unsigned short f2bf(float f) {
    unsigned u = __float_as_uint(f);
    u += 0x7FFFu + ((u >> 16) & 1u);
    return (unsigned short)(u >> 16);
}

// async global->LDS, 16B per lane; dest must be wave-uniform base (+lane*16 by HW)
#define GLL16(g, l) \
    __builtin_amdgcn_global_load_lds((const __attribute__((address_space(1))) unsigned int*)(g), \
                                     (__attribute__((address_space(3))) unsigned int*)(l), 16, 0, 0)

// ---------------- routing device helper (single block's worth of work) ----------------
__device__ __forceinline__ void route_body(const int* __restrict__ idx,
                                           const float* __restrict__ wts,
                                           int* __restrict__ counts_g,
                                           int* __restrict__ btok,
                                           float* __restrict__ bw,
                                           int* __restrict__ offs_g,
                                           int* __restrict__ slotmap,
                                           int* __restrict__ gu_tab,
                                           int* __restrict__ dn_tab) {
    __shared__ int h[NEXP], nt[NEXP], pre[NEXP], base[NEXP], cur[NEXP];
    const int tid = threadIdx.x;
    if (tid < NEXP) { h[tid] = 0; cur[tid] = 0; }
    __syncthreads();
    for (int s = tid; s < NSLOT; s += 256) atomicAdd(&h[idx[s]], 1);
    __syncthreads();
    if (tid == 0) {
        int a = 0;
        for (int e = 0; e < NEXP; ++e) {
            base[e] = a; counts_g[e] = h[e]; offs_g[e] = a;
            int t = (h[e] + 127) >> 7; nt[e] = t; a += t << 7;
        }
        int p = 0;
        for (int e = 0; e < NEXP; ++e) { pre[e] = p; p += nt[e]; }
    }
    __syncthreads();
    for (int s = tid; s < NSLOT; s += 256) {
        int e = idx[s];
        int p = atomicAdd(&cur[e], 1);
        btok[e * NSLOT + p] = s >> 1;          // token id (TOPK=2)
        bw[e * NSLOT + p] = wts[s];
        slotmap[s] = base[e] + p;              // global compact row
    }
    for (int i = tid; i < 8 * SLOTS; i += 256) { gu_tab[i] = -1; dn_tab[i] = -1; }
    __syncthreads();
    if (tid < 128) {
        int c = tid, e = c >> 4, ib = c & 15;
        int sb = 2 * pre[e] + (ib >> 3) * nt[e];
        for (int j = 0; j < nt[e]; ++j)
            gu_tab[(sb + j) * 8 + (ib & 7)] = (e << 16) | (ib << 8) | j;
    } else if (tid < 256) {
        int c = tid - 128, e = c >> 4, ib = c & 15;
        int sb = 2 * pre[e] + (ib >> 3) * nt[e];
        for (int j = 0; j < nt[e]; ++j)
            dn_tab[(sb + j) * 8 + (ib & 7)] = (e << 16) | (ib << 8) | j;
    }
}

__global__ void route_all_k(const int* __restrict__ idx, const float* __restrict__ wts,
                            int* __restrict__ counts_g, int* __restrict__ btok,
                            float* __restrict__ bw, int* __restrict__ offs_g,
                            int* __restrict__ slotmap, int* __restrict__ gu_tab,
                            int* __restrict__ dn_tab) {
    route_body(idx, wts, counts_g, btok, bw, offs_g, slotmap, gu_tab, dn_tab);
}

// ---------------- fp32 -> bf16 conversion ----------------
__device__ __forceinline__ void cvt8(const float* __restrict__ src,
                                     unsigned short* __restrict__ dst, size_t o) {
    const float4* s4 = (const float4*)src + o * 2;
    float4 a = s4[0], b = s4[1];
    union { unsigned short s[8]; uint4 v; } r;
    r.s[0] = f2bf(a.x); r.s[1] = f2bf(a.y); r.s[2] = f2bf(a.z); r.s[3] = f2bf(a.w);
    r.s[4] = f2bf(b.x); r.s[5] = f2bf(b.y); r.s[6] = f2bf(b.z); r.s[7] = f2bf(b.w);
    ((uint4*)dst)[o] = r.v;
}

// tier-1: routing (block 0) + convert x, gate, up, down (remaining blocks)
__global__ void prep_all_k(const float* __restrict__ x, const float* __restrict__ g,
                           const float* __restrict__ u, const float* __restrict__ d,
                           const int* __restrict__ idx, const float* __restrict__ wts,
                           unsigned short* __restrict__ xb, unsigned short* __restrict__ gb,
                           unsigned short* __restrict__ ub, unsigned short* __restrict__ db,
                           int* __restrict__ counts_g, int* __restrict__ btok,
                           float* __restrict__ bw, int* __restrict__ offs_g,
                           int* __restrict__ slotmap, int* __restrict__ gu_tab,
                           int* __restrict__ dn_tab) {
    if (blockIdx.x == 0) {
        route_body(idx, wts, counts_g, btok, bw, offs_g, slotmap, gu_tab, dn_tab);
        return;
    }
    size_t j = (size_t)(blockIdx.x - 1) * 256 + threadIdx.x;
    const size_t X8 = (size_t)NTOK * HID / 8;
    const size_t W8 = (size_t)NEXP * ITR * HID / 8;
    if (j < X8)                cvt8(x, xb, j);
    else if (j < X8 + W8)      cvt8(g, gb, j - X8);
    else if (j < X8 + 2 * W8)  cvt8(u, ub, j - X8 - W8);
    else                       cvt8(d, db, j - X8 - 2 * W8);
}

// tier-2 conversion kernels
__global__ void cvt_gux_k(const float* __restrict__ x, const float* __restrict__ g,
                          const float* __restrict__ u,
                          unsigned short* __restrict__ xb, unsigned short* __restrict__ gb,
                          unsigned short* __restrict__ ub) {
    size_t j = (size_t)blockIdx.x * 256 + threadIdx.x;
    const size_t X8 = (size_t)NTOK * HID / 8;
    const size_t W8 = (size_t)NEXP * ITR * HID / 8;
    if (j < X8)           cvt8(x, xb, j);
    else if (j < X8 + W8) cvt8(g, gb, j - X8);
    else                  cvt8(u, ub, j - X8 - W8);
}

__global__ void cvt_dn_k(const float* __restrict__ d, unsigned short* __restrict__ db) {
    size_t j = (size_t)blockIdx.x * 256 + threadIdx.x;
    cvt8(d, db, j);
}

// combine: out[t] = part[slot0[t]] + part[slot1[t]]  (weights already applied)
__global__ void combine_k(const float* __restrict__ part,
                          const int* __restrict__ slotmap,
                          float* __restrict__ out) {
    int gid = blockIdx.x * 256 + threadIdx.x;
    int t = gid >> 9;
    int c = gid & 511;
    int s0 = slotmap[t * 2], s1 = slotmap[t * 2 + 1];
    float4 a = ((const float4*)part)[(size_t)s0 * 512 + c];
    float4 b = ((const float4*)part)[(size_t)s1 * 512 + c];
    float4 r; r.x = a.x + b.x; r.y = a.y + b.y; r.z = a.z + b.z; r.w = a.w + b.w;
    ((float4*)out)[gid] = r;
}

// ================= bf16 MFMA path: double-buffered LDS + T3-min schedule =================
#define BK 64

// Stage 1: M=128 slots x N=64 inter cols (gate & up), K=2048. grid = 8*SLOTS via gu_tab
// T3-min: STAGE(next buf) issued BEFORE compute; single vmcnt(0)+s_barrier per K-step AFTER compute.
__launch_bounds__(256)
__global__ void moe_gu_bf_k(const unsigned short* __restrict__ xb,
                            const unsigned short* __restrict__ gateb,
                            const unsigned short* __restrict__ upb,
                            const int* __restrict__ counts,
                            const int* __restrict__ btok,
                            const int* __restrict__ off,
                            const int* __restrict__ gu_tab,
                            unsigned short* __restrict__ interw) {
    const int v = gu_tab[blockIdx.x];
    if (v < 0) return;
    const int e    = v >> 16;
    const int iblk = (v >> 8) & 255;
    const int tile = v & 255;
    const int n = counts[e];

    __shared__ unsigned short s_a[2 * 128 * 64];   // dbuf, 8192 shorts/buf
    __shared__ unsigned short s_bg[2 * 64 * 64];   // dbuf, 4096 shorts/buf
    __shared__ unsigned short s_bu[2 * 64 * 64];
    __shared__ int s_tok[128];

    const int tid = threadIdx.x;
    if (tid < 128) {
        int tt = tile * 128 + tid;
        s_tok[tid] = btok[e * NSLOT + (tt < n ? tt : n - 1)];
    }
    __syncthreads();

    const int w = tid >> 6;
    const int lane = tid & 63;

    // A staging: 4 insts x 256 threads x 16B = 128 rows x 128B (per buffer)
    const char* asrc[4]; unsigned aoff[4];
    #pragma unroll
    for (int t = 0; t < 4; ++t) {
        int c = tid + t * 256;
        int r = c >> 3;
        unsigned sw = ((unsigned)(c & 7) * 16u) ^ (((unsigned)r & 7u) << 4);
        asrc[t] = (const char*)xb + (size_t)s_tok[r] * (HID * 2) + sw;
        aoff[t] = (unsigned)(t * 256 + w * 64) * 8;   // shorts, wave-uniform base
    }
    const char* gB = (const char*)gateb + ((size_t)e * ITR + (size_t)iblk * 64) * (HID * 2);
    const char* uB = (const char*)upb   + ((size_t)e * ITR + (size_t)iblk * 64) * (HID * 2);
    const char* gsrc[2]; const char* usrc[2]; unsigned boff[2];
    #pragma unroll
    for (int t = 0; t < 2; ++t) {
        int c = tid + t * 256;
        int r = c >> 3;
        unsigned sw = ((unsigned)(c & 7) * 16u) ^ (((unsigned)r & 7u) << 4);
        gsrc[t] = gB + (size_t)r * (HID * 2) + sw;
        usrc[t] = uB + (size_t)r * (HID * 2) + sw;
        boff[t] = (unsigned)(t * 256 + w * 64) * 8;
    }

    const int wm = (w & 1) * 64, wn = (w >> 1) * 32;
    const int l15 = lane & 15, quad = lane >> 4;

    f32x4 accg[4][2], accu[4][2];
    #pragma unroll
    for (int m = 0; m < 4; ++m)
        #pragma unroll
        for (int nn = 0; nn < 2; ++nn) {
            accg[m][nn] = (f32x4){0.f, 0.f, 0.f, 0.f};
            accu[m][nn] = (f32x4){0.f, 0.f, 0.f, 0.f};
        }

    // prologue: stage k=0 into buf 0, drain, join
    #pragma unroll
    for (int t = 0; t < 4; ++t) GLL16(asrc[t], s_a + aoff[t]);
    #pragma unroll
    for (int t = 0; t < 2; ++t) { GLL16(gsrc[t], s_bg + boff[t]); GLL16(usrc[t], s_bu + boff[t]); }
    asm volatile("s_waitcnt vmcnt(0)" ::: "memory");
    __builtin_amdgcn_s_barrier();

    int cur = 0;
    for (int k0 = 0; k0 < HID; k0 += BK) {
        // issue next-tile staging into the other buffer (stays in flight across compute)
        if (k0 + BK < HID) {
            const int kb = (k0 + BK) * 2;
            const unsigned bo_a = (unsigned)(cur ^ 1) * 8192;
            const unsigned bo_b = (unsigned)(cur ^ 1) * 4096;
            #pragma unroll
            for (int t = 0; t < 4; ++t) GLL16(asrc[t] + kb, s_a + bo_a + aoff[t]);
            #pragma unroll
            for (int t = 0; t < 2; ++t) {
                GLL16(gsrc[t] + kb, s_bg + bo_b + boff[t]);
                GLL16(usrc[t] + kb, s_bu + bo_b + boff[t]);
            }
        }
        // compute current buffer
        const unsigned short* pa = s_a + (unsigned)cur * 8192;
        const unsigned short* pg = s_bg + (unsigned)cur * 4096;
        const unsigned short* pu = s_bu + (unsigned)cur * 4096;
        #pragma unroll
        for (int kk = 0; kk < 2; ++kk) {
            const unsigned kbyte = (unsigned)(kk * 64 + quad * 16);
            short8 af[4], bg[2], bu[2];
            #pragma unroll
            for (int m = 0; m < 4; ++m) {
                unsigned r = (unsigned)(wm + m * 16 + l15);
                af[m] = *(const short8*)&pa[r * 64 + ((kbyte ^ ((r & 7u) << 4)) >> 1)];
            }
            #pragma unroll
            for (int nn = 0; nn < 2; ++nn) {
                unsigned r = (unsigned)(wn + nn * 16 + l15);
                unsigned co = (kbyte ^ ((r & 7u) << 4)) >> 1;
                bg[nn] = *(const short8*)&pg[r * 64 + co];
                bu[nn] = *(const short8*)&pu[r * 64 + co];
            }
            #pragma unroll
            for (int m = 0; m < 4; ++m)
                #pragma unroll
                for (int nn = 0; nn < 2; ++nn) {
                    accg[m][nn] = __builtin_amdgcn_mfma_f32_16x16x32_bf16(af[m], bg[nn], accg[m][nn], 0, 0, 0);
                    accu[m][nn] = __builtin_amdgcn_mfma_f32_16x16x32_bf16(af[m], bu[nn], accu[m][nn], 0, 0, 0);
                }
        }
        // next-tile loads done by now (flew under MFMA); release buffers
        asm volatile("s_waitcnt vmcnt(0)" ::: "memory");
        __builtin_amdgcn_s_barrier();
        cur ^= 1;
    }

    const int pos0 = off[e] + tile * 128;
    #pragma unroll
    for (int m = 0; m < 4; ++m) {
        #pragma unroll
        for (int nn = 0; nn < 2; ++nn) {
            int col = iblk * 64 + wn + nn * 16 + l15;
            #pragma unroll
            for (int r = 0; r < 4; ++r) {
                int row = wm + m * 16 + quad * 4 + r;
                float g = accg[m][nn][r], u = accu[m][nn][r];
                float s = g / (1.0f + __expf(-g));
                interw[(size_t)(pos0 + row) * ITR + col] = f2bf(s * u);
            }
        }
    }
}

// Stage 2: M=128 slots x N=128 hid cols, K=1024. grid = 8*SLOTS via dn_tab
__launch_bounds__(256)
__global__ void moe_down_bf_k(const unsigned short* __restrict__ interw,
                              const unsigned short* __restrict__ downb,
                              const int* __restrict__ counts,
                              const int* __restrict__ btok,
                              const float* __restrict__ bw,
                              const int* __restrict__ off,
                              const int* __restrict__ dn_tab,
                              float* __restrict__ dst,
                              int mode) {
    const int v = dn_tab[blockIdx.x];
    if (v < 0) return;
    const int e    = v >> 16;
    const int hblk = (v >> 8) & 255;
    const int tile = v & 255;
    const int n = counts[e];

    __shared__ unsigned short s_a[2 * 128 * 64];
    __shared__ unsigned short s_b[2 * 128 * 64];
    __shared__ int s_tok[128];
    __shared__ float s_w[128];

    const int tid = threadIdx.x;
    if (tid < 128) {
        int tt = tile * 128 + tid;
        bool vv = tt < n;
        s_tok[tid] = btok[e * NSLOT + (vv ? tt : n - 1)];
        s_w[tid] = vv ? bw[e * NSLOT + tt] : 0.0f;
    }
    __syncthreads();

    const int w = tid >> 6;
    const int lane = tid & 63;
    const int pos0 = off[e] + tile * 128;

    const char* asrc[4]; const char* bsrc[4]; unsigned loff[4];
    const char* dB = (const char*)downb + ((size_t)e * HID + (size_t)hblk * 128) * (ITR * 2);
    #pragma unroll
    for (int t = 0; t < 4; ++t) {
        int c = tid + t * 256;
        int r = c >> 3;
        unsigned sw = ((unsigned)(c & 7) * 16u) ^ (((unsigned)r & 7u) << 4);
        asrc[t] = (const char*)interw + (size_t)(pos0 + r) * (ITR * 2) + sw;
        bsrc[t] = dB + (size_t)r * (ITR * 2) + sw;
        loff[t] = (unsigned)(t * 256 + w * 64) * 8;
    }

    const int wm = (w & 1) * 64, wn = (w >> 1) * 64;
    const int l15 = lane & 15, quad = lane >> 4;

    f32x4 acc[4][4];
    #pragma unroll
    for (int m = 0; m < 4; ++m)
        #pragma unroll
        for (int nn = 0; nn < 4; ++nn) acc[m][nn] = (f32x4){0.f, 0.f, 0.f, 0.f};

    // prologue
    #pragma unroll
    for (int t = 0; t < 4; ++t) GLL16(asrc[t], s_a + loff[t]);
    #pragma unroll
    for (int t = 0; t < 4; ++t) GLL16(bsrc[t], s_b + loff[t]);
    asm volatile("s_waitcnt vmcnt(0)" ::: "memory");
    __builtin_amdgcn_s_barrier();

    int cur = 0;
    for (int k0 = 0; k0 < ITR; k0 += BK) {
        if (k0 + BK < ITR) {
            const int kb = (k0 + BK) * 2;
            const unsigned bo = (unsigned)(cur ^ 1) * 8192;
            #pragma unroll
            for (int t = 0; t < 4; ++t) GLL16(asrc[t] + kb, s_a + bo + loff[t]);
            #pragma unroll
            for (int t = 0; t < 4; ++t) GLL16(bsrc[t] + kb, s_b + bo + loff[t]);
        }
        const unsigned short* pa = s_a + (unsigned)cur * 8192;
        const unsigned short* pb = s_b + (unsigned)cur * 8192;
        #pragma unroll
        for (int kk = 0; kk < 2; ++kk) {
            const unsigned kbyte = (unsigned)(kk * 64 + quad * 16);
            short8 af[4], bf[4];
            #pragma unroll
            for (int m = 0; m < 4; ++m) {
                unsigned r = (unsigned)(wm + m * 16 + l15);
                af[m] = *(const short8*)&pa[r * 64 + ((kbyte ^ ((r & 7u) << 4)) >> 1)];
            }
            #pragma unroll
            for (int nn = 0; nn < 4; ++nn) {
                unsigned r = (unsigned)(wn + nn * 16 + l15);
                bf[nn] = *(const short8*)&pb[r * 64 + ((kbyte ^ ((r & 7u) << 4)) >> 1)];
            }
            #pragma unroll
            for (int m = 0; m < 4; ++m)
                #pragma unroll
                for (int nn = 0; nn < 4; ++nn)
                    acc[m][nn] = __builtin_amdgcn_mfma_f32_16x16x32_bf16(af[m], bf[nn], acc[m][nn], 0, 0, 0);
        }
        asm volatile("s_waitcnt vmcnt(0)" ::: "memory");
        __builtin_amdgcn_s_barrier();
        cur ^= 1;
    }

    if (mode == 0) {
        #pragma unroll
        for (int m = 0; m < 4; ++m) {
            #pragma unroll
            for (int nn = 0; nn < 4; ++nn) {
                int col = hblk * 128 + wn + nn * 16 + l15;
                #pragma unroll
                for (int r = 0; r < 4; ++r) {
                    int row = wm + m * 16 + quad * 4 + r;
                    dst[(size_t)(pos0 + row) * HID + col] = s_w[row] * acc[m][nn][r];
                }
            }
        }
    } else {
        #pragma unroll
        for (int m = 0; m < 4; ++m) {
            #pragma unroll
            for (int nn = 0; nn < 4; ++nn) {
                int col = hblk * 128 + wn + nn * 16 + l15;
                #pragma unroll
                for (int r = 0; r < 4; ++r) {
                    int row = wm + m * 16 + quad * 4 + r;
                    atomicAdd(&dst[(size_t)s_tok[row] * HID + col], s_w[row] * acc[m][nn][r]);
                }
            }
        }
    }
}

// ================= legacy MFMA path (fallback when ws too small for bf16 weights) =================
#define LDW 72

__global__ void xconv_k(const float* __restrict__ x, unsigned short* __restrict__ xb) {
    int i = blockIdx.x * blockDim.x + threadIdx.x;
    float4 v = ((const float4*)x)[i];
    ushort4 b;
    b.x = f2bf(v.x); b.y = f2bf(v.y); b.z = f2bf(v.z); b.w = f2bf(v.w);
    ((ushort4*)xb)[i] = b;
}

__launch_bounds__(256)
__global__ void moe_gu_k(const unsigned short* __restrict__ xb,
                         const float* __restrict__ gate,
                         const float* __restrict__ up,
                         const int* __restrict__ counts,
                         const int* __restrict__ btok,
                         const int* __restrict__ off,
                         const int* __restrict__ gu_tab,
                         unsigned short* __restrict__ interw) {
    const int v = gu_tab[blockIdx.x];
    if (v < 0) return;
    const int e    = v >> 16;
    const int iblk = (v >> 8) & 255;
    const int tile = v & 255;
    const int n = counts[e];

    __shared__ unsigned short s_a[128][LDW];
    __shared__ unsigned short s_bg[64][LDW];
    __shared__ unsigned short s_bu[64][LDW];
    __shared__ int s_tok[128];

    const int tid = threadIdx.x;
    if (tid < 128) {
        int tt = tile * 128 + tid;
        s_tok[tid] = btok[e * NSLOT + (tt < n ? tt : n - 1)];
    }
    __syncthreads();

    const unsigned short* asrc[4];
    unsigned aoff[4];
    #pragma unroll
    for (int t = 0; t < 4; ++t) {
        int c = tid + t * 256;
        int r = c >> 3, col = (c & 7) * 8;
        asrc[t] = xb + (size_t)s_tok[r] * HID + col;
        aoff[t] = r * LDW + col;
    }
    const float* gbase = gate + (size_t)e * ITR * HID + (size_t)iblk * 64 * HID;
    const float* ubase = up   + (size_t)e * ITR * HID + (size_t)iblk * 64 * HID;
    unsigned boff[4], loff[4];
    #pragma unroll
    for (int t = 0; t < 4; ++t) {
        int f = tid + t * 256;
        int r = f >> 4, col = (f & 15) * 4;
        boff[t] = r * HID + col;
        loff[t] = r * LDW + col;
    }

    const int lane = tid & 63;
    const int w = tid >> 6;
    const int wm = (w & 1) * 64, wn = (w >> 1) * 32;
    const int l15 = lane & 15, quad = lane >> 4;

    f32x4 accg[4][2], accu[4][2];
    #pragma unroll
    for (int m = 0; m < 4; ++m)
        #pragma unroll
        for (int nn = 0; nn < 2; ++nn) {
            accg[m][nn] = (f32x4){0.f, 0.f, 0.f, 0.f};
            accu[m][nn] = (f32x4){0.f, 0.f, 0.f, 0.f};
        }

    unsigned short* s_flat_a = &s_a[0][0];
    unsigned short* s_flat_g = &s_bg[0][0];
    unsigned short* s_flat_u = &s_bu[0][0];

    uint4 pa[4];
    float4 pg[4], pu[4];
    #pragma unroll
    for (int t = 0; t < 4; ++t) {
        pa[t] = *(const uint4*)(asrc[t]);
        pg[t] = *(const float4*)(gbase + boff[t]);
        pu[t] = *(const float4*)(ubase + boff[t]);
    }

    for (int k0 = 0; k0 < HID; k0 += BK) {
        #pragma unroll
        for (int t = 0; t < 4; ++t) {
            *(uint4*)(s_flat_a + aoff[t]) = pa[t];
            ushort4 gb, ub;
            gb.x = f2bf(pg[t].x); gb.y = f2bf(pg[t].y); gb.z = f2bf(pg[t].z); gb.w = f2bf(pg[t].w);
            ub.x = f2bf(pu[t].x); ub.y = f2bf(pu[t].y); ub.z = f2bf(pu[t].z); ub.w = f2bf(pu[t].w);
            *(ushort4*)(s_flat_g + loff[t]) = gb;
            *(ushort4*)(s_flat_u + loff[t]) = ub;
        }
        __syncthreads();
        if (k0 + BK < HID) {
            #pragma unroll
            for (int t = 0; t < 4; ++t) {
                pa[t] = *(const uint4*)(asrc[t] + k0 + BK);
                pg[t] = *(const float4*)(gbase + boff[t] + k0 + BK);
                pu[t] = *(const float4*)(ubase + boff[t] + k0 + BK);
            }
        }
        #pragma unroll
        for (int kk = 0; kk < 2; ++kk) {
            const int kc = kk * 32 + quad * 8;
            short8 af[4], bg[2], bu[2];
            #pragma unroll
            for (int m = 0; m < 4; ++m)
                af[m] = *(const short8*)&s_a[wm + m * 16 + l15][kc];
            #pragma unroll
            for (int nn = 0; nn < 2; ++nn) {
                bg[nn] = *(const short8*)&s_bg[wn + nn * 16 + l15][kc];
                bu[nn] = *(const short8*)&s_bu[wn + nn * 16 + l15][kc];
            }
            #pragma unroll
            for (int m = 0; m < 4; ++m)
                #pragma unroll
                for (int nn = 0; nn < 2; ++nn) {
                    accg[m][nn] = __builtin_amdgcn_mfma_f32_16x16x32_bf16(af[m], bg[nn], accg[m][nn], 0, 0, 0);
                    accu[m][nn] = __builtin_amdgcn_mfma_f32_16x16x32_bf16(af[m], bu[nn], accu[m][nn], 0, 0, 0);
                }
        }
        __syncthreads();
    }

    const int pos0 = off[e] + tile * 128;
    #pragma unroll
    for (int m = 0; m < 4; ++m) {
        #pragma unroll
        for (int nn = 0; nn < 2; ++nn) {
            int col = iblk * 64 + wn + nn * 16 + l15;
            #pragma unroll
            for (int r = 0; r < 4; ++r) {
                int row = wm + m * 16 + quad * 4 + r;
                float g = accg[m][nn][r], u = accu[m][nn][r];
                float s = g / (1.0f + __expf(-g));
                interw[(size_t)(pos0 + row) * ITR + col] = f2bf(s * u);
            }
        }
    }
}

__launch_bounds__(256)
__global__ void moe_down_k(const unsigned short* __restrict__ interw,
                           const float* __restrict__ down,
                           const int* __restrict__ counts,
                           const int* __restrict__ btok,
                           const float* __restrict__ bw,
                           const int* __restrict__ off,
                           const int* __restrict__ dn_tab,
                           float* __restrict__ dst,
                           int mode) {
    const int v = dn_tab[blockIdx.x];
    if (v < 0) return;
    const int e    = v >> 16;
    const int hblk = (v >> 8) & 255;
    const int tile = v & 255;
    const int n = counts[e];

    __shared__ unsigned short s_a[128][LDW];
    __shared__ unsigned short s_b[128][LDW];
    __shared__ int s_tok[128];
    __shared__ float s_w[128];

    const int tid = threadIdx.x;
    if (tid < 128) {
        int tt = tile * 128 + tid;
        bool vv = tt < n;
        s_tok[tid] = btok[e * NSLOT + (vv ? tt : n - 1)];
        s_w[tid] = vv ? bw[e * NSLOT + tt] : 0.0f;
    }
    __syncthreads();

    const int pos0 = off[e] + tile * 128;
    unsigned aoff[4], asrco[4];
    #pragma unroll
    for (int t = 0; t < 4; ++t) {
        int c = tid + t * 256;
        int r = c >> 3, col = (c & 7) * 8;
        asrco[t] = (unsigned)((pos0 + r) * ITR + col);
        aoff[t] = r * LDW + col;
    }
    const float* dbase = down + (size_t)e * HID * ITR + (size_t)hblk * 128 * ITR;
    unsigned boff[8], loff[8];
    #pragma unroll
    for (int t = 0; t < 8; ++t) {
        int f = tid + t * 256;
        int r = f >> 4, col = (f & 15) * 4;
        boff[t] = r * ITR + col;
        loff[t] = r * LDW + col;
    }

    const int lane = tid & 63;
    const int w = tid >> 6;
    const int wm = (w & 1) * 64, wn = (w >> 1) * 64;
    const int l15 = lane & 15, quad = lane >> 4;

    f32x4 acc[4][4];
    #pragma unroll
    for (int m = 0; m < 4; ++m)
        #pragma unroll
        for (int nn = 0; nn < 4; ++nn) acc[m][nn] = (f32x4){0.f, 0.f, 0.f, 0.f};

    unsigned short* s_flat_a = &s_a[0][0];
    unsigned short* s_flat_b = &s_b[0][0];

    uint4 pa[4];
    float4 pb[8];
    #pragma unroll
    for (int t = 0; t < 4; ++t) pa[t] = *(const uint4*)(interw + asrco[t]);
    #pragma unroll
    for (int t = 0; t < 8; ++t) pb[t] = *(const float4*)(dbase + boff[t]);

    for (int k0 = 0; k0 < ITR; k0 += BK) {
        #pragma unroll
        for (int t = 0; t < 4; ++t)
            *(uint4*)(s_flat_a + aoff[t]) = pa[t];
        #pragma unroll
        for (int t = 0; t < 8; ++t) {
            ushort4 b;
            b.x = f2bf(pb[t].x); b.y = f2bf(pb[t].y); b.z = f2bf(pb[t].z); b.w = f2bf(pb[t].w);
            *(ushort4*)(s_flat_b + loff[t]) = b;
        }
        __syncthreads();
        if (k0 + BK < ITR) {
            #pragma unroll
            for (int t = 0; t < 4; ++t) pa[t] = *(const uint4*)(interw + asrco[t] + k0 + BK);
            #pragma unroll
            for (int t = 0; t < 8; ++t) pb[t] = *(const float4*)(dbase + boff[t] + k0 + BK);
        }
        #pragma unroll
        for (int kk = 0; kk < 2; ++kk) {
            const int kc = kk * 32 + quad * 8;
            short8 af[4], bf[4];
            #pragma unroll
            for (int m = 0; m < 4; ++m)
                af[m] = *(const short8*)&s_a[wm + m * 16 + l15][kc];
            #pragma unroll
            for (int nn = 0; nn < 4; ++nn)
                bf[nn] = *(const short8*)&s_b[wn + nn * 16 + l15][kc];
            #pragma unroll
            for (int m = 0; m < 4; ++m)
                #pragma unroll
                for (int nn = 0; nn < 4; ++nn)
                    acc[m][nn] = __builtin_amdgcn_mfma_f32_16x16x32_bf16(af[m], bf[nn], acc[m][nn], 0, 0, 0);
        }
        __syncthreads();
    }

    if (mode == 0) {
        #pragma unroll
        for (int m = 0; m < 4; ++m) {
            #pragma unroll
            for (int nn = 0; nn < 4; ++nn) {
                int col = hblk * 128 + wn + nn * 16 + l15;
                #pragma unroll
                for (int r = 0; r < 4; ++r) {
                    int row = wm + m * 16 + quad * 4 + r;
                    dst[(size_t)(pos0 + row) * HID + col] = s_w[row] * acc[m][nn][r];
                }
            }
        }
    } else {
        #pragma unroll
        for (int m = 0; m < 4; ++m) {
            #pragma unroll
            for (int nn = 0; nn < 4; ++nn) {
                int col = hblk * 128 + wn + nn * 16 + l15;
                #pragma unroll
                for (int r = 0; r < 4; ++r) {
                    int row = wm + m * 16 + quad * 4 + r;
                    atomicAdd(&dst[(size_t)s_tok[row] * HID + col], s_w[row] * acc[m][nn][r]);
                }
            }
        }
    }
}

// ================= fp32 fallback (used only if ws too small) =================
#define TT 8
#define TN 128
#define TK 16
#define WPAD 20
#define IPAD 1028
#define MAXTILES (NSLOT / TT)

__global__ void route_k(const int* __restrict__ idx,
                        const float* __restrict__ wts,
                        int* __restrict__ counts,
                        int* __restrict__ btok,
                        float* __restrict__ bw) {
    int s = blockIdx.x * blockDim.x + threadIdx.x;
    if (s >= NSLOT) return;
    int e = idx[s];
    int pos = atomicAdd(&counts[e], 1);
    btok[(size_t)e * NSLOT + pos] = s / TOPK;
    bw[(size_t)e * NSLOT + pos] = wts[s];
}

__launch_bounds__(256)
__global__ void moe_k(const float* __restrict__ x,
                      const float* __restrict__ gate,
                      const float* __restrict__ up,
                      const float* __restrict__ down,
                      const int* __restrict__ counts,
                      const int* __restrict__ btok,
                      const float* __restrict__ bw,
                      float* __restrict__ out) {
    const int e = blockIdx.x / MAXTILES;
    const int tile = blockIdx.x % MAXTILES;
    const int n = counts[e];
    const int t0 = tile * TT;
    if (t0 >= n) return;

    __shared__ float s_wg[TN][WPAD];
    __shared__ float s_wu[TN][WPAD];
    __shared__ float s_it[TT][IPAD];
    __shared__ int   s_tok[TT];
    __shared__ float s_w[TT];

    const int tid = threadIdx.x;
    if (tid < TT) {
        int tt = t0 + tid;
        bool v = tt < n;
        s_tok[tid] = btok[(size_t)e * NSLOT + (v ? tt : t0)];
        s_w[tid] = v ? bw[(size_t)e * NSLOT + tt] : 0.0f;
    }
    __syncthreads();

    const int tok = tid >> 5;
    const int ic  = (tid & 31) << 2;
    const int mytok = s_tok[tok];
    const float* xrow = x + (size_t)mytok * HID;
    const float* gbase = gate + (size_t)e * ITR * HID;
    const float* ubase = up   + (size_t)e * ITR * HID;
    const float* dbase = down + (size_t)e * HID * ITR;

    for (int i0 = 0; i0 < ITR; i0 += TN) {
        float ag[4] = {0.f, 0.f, 0.f, 0.f};
        float au[4] = {0.f, 0.f, 0.f, 0.f};
        for (int k0 = 0; k0 < HID; k0 += TK) {
            #pragma unroll
            for (int j = 0; j < 2; ++j) {
                int f4 = tid + j * 256;
                int r = f4 >> 2, c = (f4 & 3) << 2;
                *(float4*)&s_wg[r][c] = *(const float4*)(gbase + (size_t)(i0 + r) * HID + k0 + c);
                *(float4*)&s_wu[r][c] = *(const float4*)(ubase + (size_t)(i0 + r) * HID + k0 + c);
            }
            __syncthreads();
            #pragma unroll
            for (int kk = 0; kk < TK; kk += 4) {
                float4 xv = *(const float4*)(xrow + k0 + kk);
                #pragma unroll
                for (int q = 0; q < 4; ++q) {
                    float4 wg = *(const float4*)&s_wg[ic + q][kk];
                    float4 wu = *(const float4*)&s_wu[ic + q][kk];
                    ag[q] += xv.x * wg.x + xv.y * wg.y + xv.z * wg.z + xv.w * wg.w;
                    au[q] += xv.x * wu.x + xv.y * wu.y + xv.z * wu.z + xv.w * wu.w;
                }
            }
            __syncthreads();
        }
        #pragma unroll
        for (int q = 0; q < 4; ++q) {
            float g = ag[q], u = au[q];
            s_it[tok][i0 + ic + q] = (g / (1.0f + __expf(-g))) * u;
        }
    }
    __syncthreads();

    const float wscale = s_w[tok];
    for (int h0 = 0; h0 < HID; h0 += TN) {
        float ac[4] = {0.f, 0.f, 0.f, 0.f};
        for (int k0 = 0; k0 < ITR; k0 += TK) {
            #pragma unroll
            for (int j = 0; j < 2; ++j) {
                int f4 = tid + j * 256;
                int r = f4 >> 2, c = (f4 & 3) << 2;
                *(float4*)&s_wg[r][c] = *(const float4*)(dbase + (size_t)(h0 + r) * ITR + k0 + c);
            }
            __syncthreads();
            #pragma unroll
            for (int kk = 0; kk < TK; kk += 4) {
                float4 xv = *(const float4*)&s_it[tok][k0 + kk];
                #pragma unroll
                for (int q = 0; q < 4; ++q) {
                    float4 wv = *(const float4*)&s_wg[ic + q][kk];
                    ac[q] += xv.x * wv.x + xv.y * wv.y + xv.z * wv.z + xv.w * wv.w;
                }
            }
            __syncthreads();
        }
        float* orow = out + (size_t)mytok * HID + h0 + ic;
        #pragma unroll
        for (int q = 0; q < 4; ++q) atomicAdd(&orow[q], wscale * ac[q]);
    }
}

extern "C" void kernel_launch(void* const* d_in, const int* in_sizes, int n_in,
                              void* d_out, int out_size, void* d_ws, size_t ws_size,
                              hipStream_t stream) {
    const float* x    = (const float*)d_in[0];
    const int*   idx  = (const int*)d_in[1];
    const float* wts  = (const float*)d_in[2];
    const float* gate = (const float*)d_in[3];
    const float* up   = (const float*)d_in[4];
    const float* down = (const float*)d_in[5];
    float* out = (float*)d_out;

    // ---- common small region ----
    const size_t off_btok  = 256;
    const size_t off_bw    = off_btok + (size_t)NEXP * NSLOT * 4;      // 128 KB
    const size_t off_offs  = off_bw + (size_t)NEXP * NSLOT * 4;        // 128 KB
    const size_t off_smap  = off_offs + 256;
    const size_t off_tabs  = off_smap + (size_t)NSLOT * 4;             // 16 KB
    const size_t off_xb    = off_tabs + 2 * 8 * SLOTS * 4;             // 5.1 KB

    const size_t XBSZ  = (size_t)NTOK * HID * 2;          //  8.39 MB
    const size_t WSZ   = (size_t)NEXP * ITR * HID * 2;    // 33.55 MB each
    const size_t INTSZ = (size_t)(MAXTT * 128) * ITR * 2; // 10.49 MB
    const size_t PARTSZ = (size_t)(MAXTT * 128) * HID * 4; // 41.94 MB

    // ---- legacy layout (fallback tiers) ----
    const size_t off_inter_o = off_xb + XBSZ;
    const size_t off_part_o  = off_inter_o + INTSZ;
    const size_t need_mid  = off_part_o;
    const size_t need_full = off_part_o + PARTSZ;

    // ---- tier-2 bf16 layout (db aliases xb/gb-head, part aliases gb-tail/ub) ----
    const size_t off_gb2      = off_xb + XBSZ;
    const size_t off_ub2      = off_gb2 + WSZ;
    const size_t off_inter_n  = off_ub2 + WSZ;
    const size_t off_db2      = off_xb;            // dead after gu
    const size_t off_part2    = off_db2 + WSZ;     // gb tail + ub, dead after gu
    const size_t need_bf      = off_inter_n + INTSZ;   // ~86.3 MB

    // ---- tier-1 bf16 layout (all weights separate; single prep kernel) ----
    const size_t off_gb1    = off_xb + XBSZ;
    const size_t off_ub1    = off_gb1 + WSZ;
    const size_t off_db1    = off_ub1 + WSZ;
    const size_t off_int1   = off_db1 + WSZ;
    const size_t off_part1  = off_gb1;             // gb+ub dead after gu (67.1 MB >= 41.9)
    const size_t need_bf1   = off_int1 + INTSZ;    // ~119.8 MB

    int*   counts = (int*)d_ws;
    int*   btok   = (int*)((char*)d_ws + off_btok);
    float* bwp    = (float*)((char*)d_ws + off_bw);
    int*   offs   = (int*)((char*)d_ws + off_offs);
    int*   smap   = (int*)((char*)d_ws + off_smap);
    int*   gu_tab = (int*)((char*)d_ws + off_tabs);
    int*   dn_tab = gu_tab + 8 * SLOTS;
    unsigned short* xb = (unsigned short*)((char*)d_ws + off_xb);

    if (ws_size >= need_bf1) {
        unsigned short* gb     = (unsigned short*)((char*)d_ws + off_gb1);
        unsigned short* ub     = (unsigned short*)((char*)d_ws + off_ub1);
        unsigned short* db     = (unsigned short*)((char*)d_ws + off_db1);
        unsigned short* interw = (unsigned short*)((char*)d_ws + off_int1);
        float*          part   = (float*)((char*)d_ws + off_part1);

        const size_t X8 = (size_t)NTOK * HID / 8;
        const size_t W8 = (size_t)NEXP * ITR * HID / 8;
        const int prep_blocks = (int)((X8 + 3 * W8) / 256) + 1;   // 26625

        prep_all_k<<<dim3(prep_blocks), dim3(256), 0, stream>>>(x, gate, up, down, idx, wts,
                                                                xb, gb, ub, db,
                                                                counts, btok, bwp, offs, smap, gu_tab, dn_tab);
        moe_gu_bf_k<<<dim3(8 * SLOTS), dim3(256), 0, stream>>>(xb, gb, ub, counts, btok, offs, gu_tab, interw);
        moe_down_bf_k<<<dim3(8 * SLOTS), dim3(256), 0, stream>>>(interw, db, counts, btok, bwp, offs, dn_tab, part, 0);
        combine_k<<<dim3(NTOK * HID / 4 / 256), dim3(256), 0, stream>>>(part, smap, out);
    } else if (ws_size >= need_bf) {
        unsigned short* gb     = (unsigned short*)((char*)d_ws + off_gb2);
        unsigned short* ub     = (unsigned short*)((char*)d_ws + off_ub2);
        unsigned short* db     = (unsigned short*)((char*)d_ws + off_db2);
        unsigned short* interw = (unsigned short*)((char*)d_ws + off_inter_n);
        float*          part   = (float*)((char*)d_ws + off_part2);

        const int cvt1_blocks = (int)(((size_t)NTOK * HID / 8 + 2 * (WSZ / 16)) / 256); // 18432
        const int cvt2_blocks = (int)((WSZ / 16) / 256);                                 // 8192

        route_all_k<<<dim3(1), dim3(256), 0, stream>>>(idx, wts, counts, btok, bwp, offs, smap, gu_tab, dn_tab);
        cvt_gux_k<<<dim3(cvt1_blocks), dim3(256), 0, stream>>>(x, gate, up, xb, gb, ub);
        moe_gu_bf_k<<<dim3(8 * SLOTS), dim3(256), 0, stream>>>(xb, gb, ub, counts, btok, offs, gu_tab, interw);
        cvt_dn_k<<<dim3(cvt2_blocks), dim3(256), 0, stream>>>(down, db);
        moe_down_bf_k<<<dim3(8 * SLOTS), dim3(256), 0, stream>>>(interw, db, counts, btok, bwp, offs, dn_tab, part, 0);
        combine_k<<<dim3(NTOK * HID / 4 / 256), dim3(256), 0, stream>>>(part, smap, out);
    } else if (ws_size >= need_mid) {
        const int full = (ws_size >= need_full);
        unsigned short* interw = (unsigned short*)((char*)d_ws + off_inter_o);
        float* part   = (float*)((char*)d_ws + off_part_o);
        route_all_k<<<dim3(1), dim3(256), 0, stream>>>(idx, wts, counts, btok, bwp, offs, smap, gu_tab, dn_tab);
        xconv_k<<<dim3(NTOK * HID / 4 / 256), dim3(256), 0, stream>>>(x, xb);
        if (!full) hipMemsetAsync(d_out, 0, (size_t)out_size * sizeof(float), stream);
        moe_gu_k<<<dim3(8 * SLOTS), dim3(256), 0, stream>>>(xb, gate, up, counts, btok, offs, gu_tab, interw);
        moe_down_k<<<dim3(8 * SLOTS), dim3(256), 0, stream>>>(interw, down, counts, btok, bwp, offs, dn_tab,
                                                              full ? part : out, full ? 0 : 1);
        if (full)
            combine_k<<<dim3(NTOK * HID / 4 / 256), dim3(256), 0, stream>>>(part, smap, out);
    } else {
        hipMemsetAsync(d_out, 0, (size_t)out_size * sizeof(float), stream);
        hipMemsetAsync(counts, 0, 256, stream);
        route_k<<<dim3((NSLOT + 255) / 256), dim3(256), 0, stream>>>(idx, wts, counts, btok, bwp);
        moe_k<<<dim3(NEXP * MAXTILES), dim3(256), 0, stream>>>(x, gate, up, down, counts, btok, bwp, out);
    }
}

// Round 3
// 345.089 us; speedup vs baseline: 1.2763x; 1.0243x over previous
//
#include <hip/hip_runtime.h>
#include <math.h>

#define HID 2048
#define ITR 1024
#define NEXP 8
#define TOPK 2
#define NTOK 2048
#define NSLOT (NTOK * TOPK)
#define MAXTT 40        // max 128-row tiles across experts (bound 4096/128+7=39)
#define SLOTS 80        // per-XCD slot count for block tables (bound 2*39=78)
#define CVTD_BLOCKS 2048
#define PREP_BLOCKS 4096

typedef __attribute__((ext_vector_type(8))) short short8;
typedef __attribute__((ext_vector_type(4))) float f32x4;

__device__ __forceinline__ unsigned short f2bf(float f) {
    unsigned u = __float_as_uint(f);
    u += 0x7FFFu + ((u >> 16) & 1u);
    return (unsigned short)(u >> 16);
}

// async global->LDS, 16B per lane; dest must be wave-uniform base (+lane*16 by HW)
#define GLL16(g, l) \
    __builtin_amdgcn_global_load_lds((const __attribute__((address_space(1))) unsigned int*)(g), \
                                     (__attribute__((address_space(3))) unsigned int*)(l), 16, 0, 0)

// ---------------- routing device helper (single block's worth of work) ----------------
__device__ __forceinline__ void route_body(const int* __restrict__ idx,
                                           const float* __restrict__ wts,
                                           int* __restrict__ counts_g,
                                           int* __restrict__ btok,
                                           float* __restrict__ bw,
                                           int* __restrict__ offs_g,
                                           int* __restrict__ slotmap,
                                           int* __restrict__ gu_tab,
                                           int* __restrict__ dn_tab) {
    __shared__ int h[NEXP], nt[NEXP], pre[NEXP], base[NEXP], cur[NEXP];
    const int tid = threadIdx.x;
    if (tid < NEXP) { h[tid] = 0; cur[tid] = 0; }
    __syncthreads();
    for (int s = tid; s < NSLOT; s += 256) atomicAdd(&h[idx[s]], 1);
    __syncthreads();
    if (tid == 0) {
        int a = 0;
        for (int e = 0; e < NEXP; ++e) {
            base[e] = a; counts_g[e] = h[e]; offs_g[e] = a;
            int t = (h[e] + 127) >> 7; nt[e] = t; a += t << 7;
        }
        int p = 0;
        for (int e = 0; e < NEXP; ++e) { pre[e] = p; p += nt[e]; }
    }
    __syncthreads();
    for (int s = tid; s < NSLOT; s += 256) {
        int e = idx[s];
        int p = atomicAdd(&cur[e], 1);
        btok[e * NSLOT + p] = s >> 1;          // token id (TOPK=2)
        bw[e * NSLOT + p] = wts[s];
        slotmap[s] = base[e] + p;              // global compact row
    }
    for (int i = tid; i < 8 * SLOTS; i += 256) { gu_tab[i] = -1; dn_tab[i] = -1; }
    __syncthreads();
    if (tid < 128) {
        int c = tid, e = c >> 4, ib = c & 15;
        int sb = 2 * pre[e] + (ib >> 3) * nt[e];
        for (int j = 0; j < nt[e]; ++j)
            gu_tab[(sb + j) * 8 + (ib & 7)] = (e << 16) | (ib << 8) | j;
    } else if (tid < 256) {
        int c = tid - 128, e = c >> 4, ib = c & 15;
        int sb = 2 * pre[e] + (ib >> 3) * nt[e];
        for (int j = 0; j < nt[e]; ++j)
            dn_tab[(sb + j) * 8 + (ib & 7)] = (e << 16) | (ib << 8) | j;
    }
}

__global__ void route_all_k(const int* __restrict__ idx, const float* __restrict__ wts,
                            int* __restrict__ counts_g, int* __restrict__ btok,
                            float* __restrict__ bw, int* __restrict__ offs_g,
                            int* __restrict__ slotmap, int* __restrict__ gu_tab,
                            int* __restrict__ dn_tab) {
    route_body(idx, wts, counts_g, btok, bw, offs_g, slotmap, gu_tab, dn_tab);
}

// ---------------- fp32 -> bf16 conversion ----------------
__device__ __forceinline__ void cvt8(const float* __restrict__ src,
                                     unsigned short* __restrict__ dst, size_t o) {
    const float4* s4 = (const float4*)src + o * 2;
    float4 a = s4[0], b = s4[1];
    union { unsigned short s[8]; uint4 v; } r;
    r.s[0] = f2bf(a.x); r.s[1] = f2bf(a.y); r.s[2] = f2bf(a.z); r.s[3] = f2bf(a.w);
    r.s[4] = f2bf(b.x); r.s[5] = f2bf(b.y); r.s[6] = f2bf(b.z); r.s[7] = f2bf(b.w);
    ((uint4*)dst)[o] = r.v;
}

// tier-1 prep: routing (block 0) + grid-stride convert of x, gate, up
__global__ void prep_all_k(const float* __restrict__ x, const float* __restrict__ g,
                           const float* __restrict__ u,
                           const int* __restrict__ idx, const float* __restrict__ wts,
                           unsigned short* __restrict__ xb, unsigned short* __restrict__ gb,
                           unsigned short* __restrict__ ub,
                           int* __restrict__ counts_g, int* __restrict__ btok,
                           float* __restrict__ bw, int* __restrict__ offs_g,
                           int* __restrict__ slotmap, int* __restrict__ gu_tab,
                           int* __restrict__ dn_tab) {
    if (blockIdx.x == 0) {
        route_body(idx, wts, counts_g, btok, bw, offs_g, slotmap, gu_tab, dn_tab);
        return;
    }
    const size_t X8 = (size_t)NTOK * HID / 8;
    const size_t W8 = (size_t)NEXP * ITR * HID / 8;
    const size_t TOT = X8 + 2 * W8;
    const size_t stride = (size_t)PREP_BLOCKS * 256;
    size_t j = (size_t)(blockIdx.x - 1) * 256 + threadIdx.x;
    for (; j + stride < TOT; j += 2 * stride) {
        size_t j2 = j + stride;
        // two independent cvt8 in flight
        if (j < X8)                cvt8(x, xb, j);
        else if (j < X8 + W8)      cvt8(g, gb, j - X8);
        else                       cvt8(u, ub, j - X8 - W8);
        if (j2 < X8)               cvt8(x, xb, j2);
        else if (j2 < X8 + W8)     cvt8(g, gb, j2 - X8);
        else                       cvt8(u, ub, j2 - X8 - W8);
    }
    if (j < TOT) {
        if (j < X8)                cvt8(x, xb, j);
        else if (j < X8 + W8)      cvt8(g, gb, j - X8);
        else                       cvt8(u, ub, j - X8 - W8);
    }
}

// tier-2 conversion kernels
__global__ void cvt_gux_k(const float* __restrict__ x, const float* __restrict__ g,
                          const float* __restrict__ u,
                          unsigned short* __restrict__ xb, unsigned short* __restrict__ gb,
                          unsigned short* __restrict__ ub) {
    size_t j = (size_t)blockIdx.x * 256 + threadIdx.x;
    const size_t X8 = (size_t)NTOK * HID / 8;
    const size_t W8 = (size_t)NEXP * ITR * HID / 8;
    if (j < X8)           cvt8(x, xb, j);
    else if (j < X8 + W8) cvt8(g, gb, j - X8);
    else                  cvt8(u, ub, j - X8 - W8);
}

__global__ void cvt_dn_k(const float* __restrict__ d, unsigned short* __restrict__ db) {
    size_t j = (size_t)blockIdx.x * 256 + threadIdx.x;
    cvt8(d, db, j);
}

// combine: out[t] = part[slot0[t]] + part[slot1[t]]  (weights already applied)
__global__ void combine_k(const float* __restrict__ part,
                          const int* __restrict__ slotmap,
                          float* __restrict__ out) {
    int gid = blockIdx.x * 256 + threadIdx.x;
    int t = gid >> 9;
    int c = gid & 511;
    int s0 = slotmap[t * 2], s1 = slotmap[t * 2 + 1];
    float4 a = ((const float4*)part)[(size_t)s0 * 512 + c];
    float4 b = ((const float4*)part)[(size_t)s1 * 512 + c];
    float4 r; r.x = a.x + b.x; r.y = a.y + b.y; r.z = a.z + b.z; r.w = a.w + b.w;
    ((float4*)out)[gid] = r;
}

// ================= bf16 MFMA path (R1-proven single-buffer structure) =================
#define BK 64

// Stage 1: M=128 slots x N=64 inter cols (gate & up), K=2048.
// grid = 8*SLOTS MFMA blocks via gu_tab, + CVTD_BLOCKS trailing blocks converting down fp32->bf16
// (BW-bound cvt co-runs with the latency-bound GEMM; MFMA blocks dispatch first).
__launch_bounds__(256)
__global__ void moe_gu_fused_k(const unsigned short* __restrict__ xb,
                               const unsigned short* __restrict__ gateb,
                               const unsigned short* __restrict__ upb,
                               const int* __restrict__ counts,
                               const int* __restrict__ btok,
                               const int* __restrict__ off,
                               const int* __restrict__ gu_tab,
                               unsigned short* __restrict__ interw,
                               const float* __restrict__ down,
                               unsigned short* __restrict__ db) {
    if (blockIdx.x >= 8 * SLOTS) {
        // grid-stride down-conversion: D8 = NEXP*HID*ITR/8 uint4-groups
        const size_t D8 = (size_t)NEXP * HID * ITR / 8;
        const size_t stride = (size_t)CVTD_BLOCKS * 256;
        size_t j = (size_t)(blockIdx.x - 8 * SLOTS) * 256 + threadIdx.x;
        for (; j + stride < D8; j += 2 * stride) {
            cvt8(down, db, j);
            cvt8(down, db, j + stride);
        }
        if (j < D8) cvt8(down, db, j);
        return;
    }
    const int v = gu_tab[blockIdx.x];
    if (v < 0) return;
    const int e    = v >> 16;
    const int iblk = (v >> 8) & 255;
    const int tile = v & 255;
    const int n = counts[e];

    __shared__ unsigned short s_a[128 * 64];   // [row][64 bf16], 128B rows, XOR-swizzled
    __shared__ unsigned short s_bg[64 * 64];
    __shared__ unsigned short s_bu[64 * 64];
    __shared__ int s_tok[128];

    const int tid = threadIdx.x;
    if (tid < 128) {
        int tt = tile * 128 + tid;
        s_tok[tid] = btok[e * NSLOT + (tt < n ? tt : n - 1)];
    }
    __syncthreads();

    const int w = tid >> 6;
    const int lane = tid & 63;

    // A staging: 4 insts x 256 threads x 16B = 128 rows x 128B
    const char* asrc[4]; unsigned short* adst[4];
    #pragma unroll
    for (int t = 0; t < 4; ++t) {
        int c = tid + t * 256;
        int r = c >> 3;
        unsigned sw = ((unsigned)(c & 7) * 16u) ^ (((unsigned)r & 7u) << 4);
        asrc[t] = (const char*)xb + (size_t)s_tok[r] * (HID * 2) + sw;
        adst[t] = s_a + (size_t)(t * 256 + w * 64) * 8;   // wave-uniform base
    }
    // B staging: 2 insts each for gate/up = 64 rows x 128B each
    const char* gB = (const char*)gateb + ((size_t)e * ITR + (size_t)iblk * 64) * (HID * 2);
    const char* uB = (const char*)upb   + ((size_t)e * ITR + (size_t)iblk * 64) * (HID * 2);
    const char* gsrc[2]; const char* usrc[2];
    unsigned short* gdst[2]; unsigned short* udst[2];
    #pragma unroll
    for (int t = 0; t < 2; ++t) {
        int c = tid + t * 256;
        int r = c >> 3;
        unsigned sw = ((unsigned)(c & 7) * 16u) ^ (((unsigned)r & 7u) << 4);
        gsrc[t] = gB + (size_t)r * (HID * 2) + sw;
        usrc[t] = uB + (size_t)r * (HID * 2) + sw;
        gdst[t] = s_bg + (size_t)(t * 256 + w * 64) * 8;
        udst[t] = s_bu + (size_t)(t * 256 + w * 64) * 8;
    }

    const int wm = (w & 1) * 64, wn = (w >> 1) * 32;
    const int l15 = lane & 15, quad = lane >> 4;

    f32x4 accg[4][2], accu[4][2];
    #pragma unroll
    for (int m = 0; m < 4; ++m)
        #pragma unroll
        for (int nn = 0; nn < 2; ++nn) {
            accg[m][nn] = (f32x4){0.f, 0.f, 0.f, 0.f};
            accu[m][nn] = (f32x4){0.f, 0.f, 0.f, 0.f};
        }

    for (int k0 = 0; k0 < HID; k0 += BK) {
        const int kb0 = k0 * 2;
        #pragma unroll
        for (int t = 0; t < 4; ++t) GLL16(asrc[t] + kb0, adst[t]);
        #pragma unroll
        for (int t = 0; t < 2; ++t) { GLL16(gsrc[t] + kb0, gdst[t]); GLL16(usrc[t] + kb0, udst[t]); }
        __syncthreads();   // compiler-managed drain: LDS tile ready
        #pragma unroll
        for (int kk = 0; kk < 2; ++kk) {
            const unsigned kbyte = (unsigned)(kk * 64 + quad * 16);
            short8 af[4], bg[2], bu[2];
            #pragma unroll
            for (int m = 0; m < 4; ++m) {
                unsigned r = (unsigned)(wm + m * 16 + l15);
                af[m] = *(const short8*)&s_a[r * 64 + ((kbyte ^ ((r & 7u) << 4)) >> 1)];
            }
            #pragma unroll
            for (int nn = 0; nn < 2; ++nn) {
                unsigned r = (unsigned)(wn + nn * 16 + l15);
                unsigned co = (kbyte ^ ((r & 7u) << 4)) >> 1;
                bg[nn] = *(const short8*)&s_bg[r * 64 + co];
                bu[nn] = *(const short8*)&s_bu[r * 64 + co];
            }
            #pragma unroll
            for (int m = 0; m < 4; ++m)
                #pragma unroll
                for (int nn = 0; nn < 2; ++nn) {
                    accg[m][nn] = __builtin_amdgcn_mfma_f32_16x16x32_bf16(af[m], bg[nn], accg[m][nn], 0, 0, 0);
                    accu[m][nn] = __builtin_amdgcn_mfma_f32_16x16x32_bf16(af[m], bu[nn], accu[m][nn], 0, 0, 0);
                }
        }
        __syncthreads();
    }

    const int pos0 = off[e] + tile * 128;
    #pragma unroll
    for (int m = 0; m < 4; ++m) {
        #pragma unroll
        for (int nn = 0; nn < 2; ++nn) {
            int col = iblk * 64 + wn + nn * 16 + l15;
            #pragma unroll
            for (int r = 0; r < 4; ++r) {
                int row = wm + m * 16 + quad * 4 + r;
                float g = accg[m][nn][r], u = accu[m][nn][r];
                float s = g / (1.0f + __expf(-g));
                interw[(size_t)(pos0 + row) * ITR + col] = f2bf(s * u);
            }
        }
    }
}

// Stage 2: M=128 slots x N=128 hid cols, K=1024. grid = 8*SLOTS via dn_tab
__launch_bounds__(256)
__global__ void moe_down_bf_k(const unsigned short* __restrict__ interw,
                              const unsigned short* __restrict__ downb,
                              const int* __restrict__ counts,
                              const int* __restrict__ btok,
                              const float* __restrict__ bw,
                              const int* __restrict__ off,
                              const int* __restrict__ dn_tab,
                              float* __restrict__ dst,
                              int mode) {
    const int v = dn_tab[blockIdx.x];
    if (v < 0) return;
    const int e    = v >> 16;
    const int hblk = (v >> 8) & 255;
    const int tile = v & 255;
    const int n = counts[e];

    __shared__ unsigned short s_a[128 * 64];
    __shared__ unsigned short s_b[128 * 64];
    __shared__ int s_tok[128];
    __shared__ float s_w[128];

    const int tid = threadIdx.x;
    if (tid < 128) {
        int tt = tile * 128 + tid;
        bool vv = tt < n;
        s_tok[tid] = btok[e * NSLOT + (vv ? tt : n - 1)];
        s_w[tid] = vv ? bw[e * NSLOT + tt] : 0.0f;
    }
    __syncthreads();

    const int w = tid >> 6;
    const int lane = tid & 63;
    const int pos0 = off[e] + tile * 128;

    const char* asrc[4]; unsigned short* adst[4];
    const char* bsrc[4]; unsigned short* bdst[4];
    const char* dB = (const char*)downb + ((size_t)e * HID + (size_t)hblk * 128) * (ITR * 2);
    #pragma unroll
    for (int t = 0; t < 4; ++t) {
        int c = tid + t * 256;
        int r = c >> 3;
        unsigned sw = ((unsigned)(c & 7) * 16u) ^ (((unsigned)r & 7u) << 4);
        asrc[t] = (const char*)interw + (size_t)(pos0 + r) * (ITR * 2) + sw;
        bsrc[t] = dB + (size_t)r * (ITR * 2) + sw;
        adst[t] = s_a + (size_t)(t * 256 + w * 64) * 8;
        bdst[t] = s_b + (size_t)(t * 256 + w * 64) * 8;
    }

    const int wm = (w & 1) * 64, wn = (w >> 1) * 64;
    const int l15 = lane & 15, quad = lane >> 4;

    f32x4 acc[4][4];
    #pragma unroll
    for (int m = 0; m < 4; ++m)
        #pragma unroll
        for (int nn = 0; nn < 4; ++nn) acc[m][nn] = (f32x4){0.f, 0.f, 0.f, 0.f};

    for (int k0 = 0; k0 < ITR; k0 += BK) {
        const int kb0 = k0 * 2;
        #pragma unroll
        for (int t = 0; t < 4; ++t) GLL16(asrc[t] + kb0, adst[t]);
        #pragma unroll
        for (int t = 0; t < 4; ++t) GLL16(bsrc[t] + kb0, bdst[t]);
        __syncthreads();
        #pragma unroll
        for (int kk = 0; kk < 2; ++kk) {
            const unsigned kbyte = (unsigned)(kk * 64 + quad * 16);
            short8 af[4], bf[4];
            #pragma unroll
            for (int m = 0; m < 4; ++m) {
                unsigned r = (unsigned)(wm + m * 16 + l15);
                af[m] = *(const short8*)&s_a[r * 64 + ((kbyte ^ ((r & 7u) << 4)) >> 1)];
            }
            #pragma unroll
            for (int nn = 0; nn < 4; ++nn) {
                unsigned r = (unsigned)(wn + nn * 16 + l15);
                bf[nn] = *(const short8*)&s_b[r * 64 + ((kbyte ^ ((r & 7u) << 4)) >> 1)];
            }
            #pragma unroll
            for (int m = 0; m < 4; ++m)
                #pragma unroll
                for (int nn = 0; nn < 4; ++nn)
                    acc[m][nn] = __builtin_amdgcn_mfma_f32_16x16x32_bf16(af[m], bf[nn], acc[m][nn], 0, 0, 0);
        }
        __syncthreads();
    }

    if (mode == 0) {
        #pragma unroll
        for (int m = 0; m < 4; ++m) {
            #pragma unroll
            for (int nn = 0; nn < 4; ++nn) {
                int col = hblk * 128 + wn + nn * 16 + l15;
                #pragma unroll
                for (int r = 0; r < 4; ++r) {
                    int row = wm + m * 16 + quad * 4 + r;
                    dst[(size_t)(pos0 + row) * HID + col] = s_w[row] * acc[m][nn][r];
                }
            }
        }
    } else {
        #pragma unroll
        for (int m = 0; m < 4; ++m) {
            #pragma unroll
            for (int nn = 0; nn < 4; ++nn) {
                int col = hblk * 128 + wn + nn * 16 + l15;
                #pragma unroll
                for (int r = 0; r < 4; ++r) {
                    int row = wm + m * 16 + quad * 4 + r;
                    atomicAdd(&dst[(size_t)s_tok[row] * HID + col], s_w[row] * acc[m][nn][r]);
                }
            }
        }
    }
}

// ================= legacy MFMA path (fallback when ws too small for bf16 weights) =================
#define LDW 72

__global__ void xconv_k(const float* __restrict__ x, unsigned short* __restrict__ xb) {
    int i = blockIdx.x * blockDim.x + threadIdx.x;
    float4 v = ((const float4*)x)[i];
    ushort4 b;
    b.x = f2bf(v.x); b.y = f2bf(v.y); b.z = f2bf(v.z); b.w = f2bf(v.w);
    ((ushort4*)xb)[i] = b;
}

__launch_bounds__(256)
__global__ void moe_gu_k(const unsigned short* __restrict__ xb,
                         const float* __restrict__ gate,
                         const float* __restrict__ up,
                         const int* __restrict__ counts,
                         const int* __restrict__ btok,
                         const int* __restrict__ off,
                         const int* __restrict__ gu_tab,
                         unsigned short* __restrict__ interw) {
    const int v = gu_tab[blockIdx.x];
    if (v < 0) return;
    const int e    = v >> 16;
    const int iblk = (v >> 8) & 255;
    const int tile = v & 255;
    const int n = counts[e];

    __shared__ unsigned short s_a[128][LDW];
    __shared__ unsigned short s_bg[64][LDW];
    __shared__ unsigned short s_bu[64][LDW];
    __shared__ int s_tok[128];

    const int tid = threadIdx.x;
    if (tid < 128) {
        int tt = tile * 128 + tid;
        s_tok[tid] = btok[e * NSLOT + (tt < n ? tt : n - 1)];
    }
    __syncthreads();

    const unsigned short* asrc[4];
    unsigned aoff[4];
    #pragma unroll
    for (int t = 0; t < 4; ++t) {
        int c = tid + t * 256;
        int r = c >> 3, col = (c & 7) * 8;
        asrc[t] = xb + (size_t)s_tok[r] * HID + col;
        aoff[t] = r * LDW + col;
    }
    const float* gbase = gate + (size_t)e * ITR * HID + (size_t)iblk * 64 * HID;
    const float* ubase = up   + (size_t)e * ITR * HID + (size_t)iblk * 64 * HID;
    unsigned boff[4], loff[4];
    #pragma unroll
    for (int t = 0; t < 4; ++t) {
        int f = tid + t * 256;
        int r = f >> 4, col = (f & 15) * 4;
        boff[t] = r * HID + col;
        loff[t] = r * LDW + col;
    }

    const int lane = tid & 63;
    const int w = tid >> 6;
    const int wm = (w & 1) * 64, wn = (w >> 1) * 32;
    const int l15 = lane & 15, quad = lane >> 4;

    f32x4 accg[4][2], accu[4][2];
    #pragma unroll
    for (int m = 0; m < 4; ++m)
        #pragma unroll
        for (int nn = 0; nn < 2; ++nn) {
            accg[m][nn] = (f32x4){0.f, 0.f, 0.f, 0.f};
            accu[m][nn] = (f32x4){0.f, 0.f, 0.f, 0.f};
        }

    unsigned short* s_flat_a = &s_a[0][0];
    unsigned short* s_flat_g = &s_bg[0][0];
    unsigned short* s_flat_u = &s_bu[0][0];

    uint4 pa[4];
    float4 pg[4], pu[4];
    #pragma unroll
    for (int t = 0; t < 4; ++t) {
        pa[t] = *(const uint4*)(asrc[t]);
        pg[t] = *(const float4*)(gbase + boff[t]);
        pu[t] = *(const float4*)(ubase + boff[t]);
    }

    for (int k0 = 0; k0 < HID; k0 += BK) {
        #pragma unroll
        for (int t = 0; t < 4; ++t) {
            *(uint4*)(s_flat_a + aoff[t]) = pa[t];
            ushort4 gb, ub;
            gb.x = f2bf(pg[t].x); gb.y = f2bf(pg[t].y); gb.z = f2bf(pg[t].z); gb.w = f2bf(pg[t].w);
            ub.x = f2bf(pu[t].x); ub.y = f2bf(pu[t].y); ub.z = f2bf(pu[t].z); ub.w = f2bf(pu[t].w);
            *(ushort4*)(s_flat_g + loff[t]) = gb;
            *(ushort4*)(s_flat_u + loff[t]) = ub;
        }
        __syncthreads();
        if (k0 + BK < HID) {
            #pragma unroll
            for (int t = 0; t < 4; ++t) {
                pa[t] = *(const uint4*)(asrc[t] + k0 + BK);
                pg[t] = *(const float4*)(gbase + boff[t] + k0 + BK);
                pu[t] = *(const float4*)(ubase + boff[t] + k0 + BK);
            }
        }
        #pragma unroll
        for (int kk = 0; kk < 2; ++kk) {
            const int kc = kk * 32 + quad * 8;
            short8 af[4], bg[2], bu[2];
            #pragma unroll
            for (int m = 0; m < 4; ++m)
                af[m] = *(const short8*)&s_a[wm + m * 16 + l15][kc];
            #pragma unroll
            for (int nn = 0; nn < 2; ++nn) {
                bg[nn] = *(const short8*)&s_bg[wn + nn * 16 + l15][kc];
                bu[nn] = *(const short8*)&s_bu[wn + nn * 16 + l15][kc];
            }
            #pragma unroll
            for (int m = 0; m < 4; ++m)
                #pragma unroll
                for (int nn = 0; nn < 2; ++nn) {
                    accg[m][nn] = __builtin_amdgcn_mfma_f32_16x16x32_bf16(af[m], bg[nn], accg[m][nn], 0, 0, 0);
                    accu[m][nn] = __builtin_amdgcn_mfma_f32_16x16x32_bf16(af[m], bu[nn], accu[m][nn], 0, 0, 0);
                }
        }
        __syncthreads();
    }

    const int pos0 = off[e] + tile * 128;
    #pragma unroll
    for (int m = 0; m < 4; ++m) {
        #pragma unroll
        for (int nn = 0; nn < 2; ++nn) {
            int col = iblk * 64 + wn + nn * 16 + l15;
            #pragma unroll
            for (int r = 0; r < 4; ++r) {
                int row = wm + m * 16 + quad * 4 + r;
                float g = accg[m][nn][r], u = accu[m][nn][r];
                float s = g / (1.0f + __expf(-g));
                interw[(size_t)(pos0 + row) * ITR + col] = f2bf(s * u);
            }
        }
    }
}

__launch_bounds__(256)
__global__ void moe_down_k(const unsigned short* __restrict__ interw,
                           const float* __restrict__ down,
                           const int* __restrict__ counts,
                           const int* __restrict__ btok,
                           const float* __restrict__ bw,
                           const int* __restrict__ off,
                           const int* __restrict__ dn_tab,
                           float* __restrict__ dst,
                           int mode) {
    const int v = dn_tab[blockIdx.x];
    if (v < 0) return;
    const int e    = v >> 16;
    const int hblk = (v >> 8) & 255;
    const int tile = v & 255;
    const int n = counts[e];

    __shared__ unsigned short s_a[128][LDW];
    __shared__ unsigned short s_b[128][LDW];
    __shared__ int s_tok[128];
    __shared__ float s_w[128];

    const int tid = threadIdx.x;
    if (tid < 128) {
        int tt = tile * 128 + tid;
        bool vv = tt < n;
        s_tok[tid] = btok[e * NSLOT + (vv ? tt : n - 1)];
        s_w[tid] = vv ? bw[e * NSLOT + tt] : 0.0f;
    }
    __syncthreads();

    const int pos0 = off[e] + tile * 128;
    unsigned aoff[4], asrco[4];
    #pragma unroll
    for (int t = 0; t < 4; ++t) {
        int c = tid + t * 256;
        int r = c >> 3, col = (c & 7) * 8;
        asrco[t] = (unsigned)((pos0 + r) * ITR + col);
        aoff[t] = r * LDW + col;
    }
    const float* dbase = down + (size_t)e * HID * ITR + (size_t)hblk * 128 * ITR;
    unsigned boff[8], loff[8];
    #pragma unroll
    for (int t = 0; t < 8; ++t) {
        int f = tid + t * 256;
        int r = f >> 4, col = (f & 15) * 4;
        boff[t] = r * ITR + col;
        loff[t] = r * LDW + col;
    }

    const int lane = tid & 63;
    const int w = tid >> 6;
    const int wm = (w & 1) * 64, wn = (w >> 1) * 64;
    const int l15 = lane & 15, quad = lane >> 4;

    f32x4 acc[4][4];
    #pragma unroll
    for (int m = 0; m < 4; ++m)
        #pragma unroll
        for (int nn = 0; nn < 4; ++nn) acc[m][nn] = (f32x4){0.f, 0.f, 0.f, 0.f};

    unsigned short* s_flat_a = &s_a[0][0];
    unsigned short* s_flat_b = &s_b[0][0];

    uint4 pa[4];
    float4 pb[8];
    #pragma unroll
    for (int t = 0; t < 4; ++t) pa[t] = *(const uint4*)(interw + asrco[t]);
    #pragma unroll
    for (int t = 0; t < 8; ++t) pb[t] = *(const float4*)(dbase + boff[t]);

    for (int k0 = 0; k0 < ITR; k0 += BK) {
        #pragma unroll
        for (int t = 0; t < 4; ++t)
            *(uint4*)(s_flat_a + aoff[t]) = pa[t];
        #pragma unroll
        for (int t = 0; t < 8; ++t) {
            ushort4 b;
            b.x = f2bf(pb[t].x); b.y = f2bf(pb[t].y); b.z = f2bf(pb[t].z); b.w = f2bf(pb[t].w);
            *(ushort4*)(s_flat_b + loff[t]) = b;
        }
        __syncthreads();
        if (k0 + BK < ITR) {
            #pragma unroll
            for (int t = 0; t < 4; ++t) pa[t] = *(const uint4*)(interw + asrco[t] + k0 + BK);
            #pragma unroll
            for (int t = 0; t < 8; ++t) pb[t] = *(const float4*)(dbase + boff[t] + k0 + BK);
        }
        #pragma unroll
        for (int kk = 0; kk < 2; ++kk) {
            const int kc = kk * 32 + quad * 8;
            short8 af[4], bf[4];
            #pragma unroll
            for (int m = 0; m < 4; ++m)
                af[m] = *(const short8*)&s_a[wm + m * 16 + l15][kc];
            #pragma unroll
            for (int nn = 0; nn < 4; ++nn)
                bf[nn] = *(const short8*)&s_b[wn + nn * 16 + l15][kc];
            #pragma unroll
            for (int m = 0; m < 4; ++m)
                #pragma unroll
                for (int nn = 0; nn < 4; ++nn)
                    acc[m][nn] = __builtin_amdgcn_mfma_f32_16x16x32_bf16(af[m], bf[nn], acc[m][nn], 0, 0, 0);
        }
        __syncthreads();
    }

    if (mode == 0) {
        #pragma unroll
        for (int m = 0; m < 4; ++m) {
            #pragma unroll
            for (int nn = 0; nn < 4; ++nn) {
                int col = hblk * 128 + wn + nn * 16 + l15;
                #pragma unroll
                for (int r = 0; r < 4; ++r) {
                    int row = wm + m * 16 + quad * 4 + r;
                    dst[(size_t)(pos0 + row) * HID + col] = s_w[row] * acc[m][nn][r];
                }
            }
        }
    } else {
        #pragma unroll
        for (int m = 0; m < 4; ++m) {
            #pragma unroll
            for (int nn = 0; nn < 4; ++nn) {
                int col = hblk * 128 + wn + nn * 16 + l15;
                #pragma unroll
                for (int r = 0; r < 4; ++r) {
                    int row = wm + m * 16 + quad * 4 + r;
                    atomicAdd(&dst[(size_t)s_tok[row] * HID + col], s_w[row] * acc[m][nn][r]);
                }
            }
        }
    }
}

// ================= fp32 fallback (used only if ws too small) =================
#define TT 8
#define TN 128
#define TK 16
#define WPAD 20
#define IPAD 1028
#define MAXTILES (NSLOT / TT)

__global__ void route_k(const int* __restrict__ idx,
                        const float* __restrict__ wts,
                        int* __restrict__ counts,
                        int* __restrict__ btok,
                        float* __restrict__ bw) {
    int s = blockIdx.x * blockDim.x + threadIdx.x;
    if (s >= NSLOT) return;
    int e = idx[s];
    int pos = atomicAdd(&counts[e], 1);
    btok[(size_t)e * NSLOT + pos] = s / TOPK;
    bw[(size_t)e * NSLOT + pos] = wts[s];
}

__launch_bounds__(256)
__global__ void moe_k(const float* __restrict__ x,
                      const float* __restrict__ gate,
                      const float* __restrict__ up,
                      const float* __restrict__ down,
                      const int* __restrict__ counts,
                      const int* __restrict__ btok,
                      const float* __restrict__ bw,
                      float* __restrict__ out) {
    const int e = blockIdx.x / MAXTILES;
    const int tile = blockIdx.x % MAXTILES;
    const int n = counts[e];
    const int t0 = tile * TT;
    if (t0 >= n) return;

    __shared__ float s_wg[TN][WPAD];
    __shared__ float s_wu[TN][WPAD];
    __shared__ float s_it[TT][IPAD];
    __shared__ int   s_tok[TT];
    __shared__ float s_w[TT];

    const int tid = threadIdx.x;
    if (tid < TT) {
        int tt = t0 + tid;
        bool v = tt < n;
        s_tok[tid] = btok[(size_t)e * NSLOT + (v ? tt : t0)];
        s_w[tid] = v ? bw[(size_t)e * NSLOT + tt] : 0.0f;
    }
    __syncthreads();

    const int tok = tid >> 5;
    const int ic  = (tid & 31) << 2;
    const int mytok = s_tok[tok];
    const float* xrow = x + (size_t)mytok * HID;
    const float* gbase = gate + (size_t)e * ITR * HID;
    const float* ubase = up   + (size_t)e * ITR * HID;
    const float* dbase = down + (size_t)e * HID * ITR;

    for (int i0 = 0; i0 < ITR; i0 += TN) {
        float ag[4] = {0.f, 0.f, 0.f, 0.f};
        float au[4] = {0.f, 0.f, 0.f, 0.f};
        for (int k0 = 0; k0 < HID; k0 += TK) {
            #pragma unroll
            for (int j = 0; j < 2; ++j) {
                int f4 = tid + j * 256;
                int r = f4 >> 2, c = (f4 & 3) << 2;
                *(float4*)&s_wg[r][c] = *(const float4*)(gbase + (size_t)(i0 + r) * HID + k0 + c);
                *(float4*)&s_wu[r][c] = *(const float4*)(ubase + (size_t)(i0 + r) * HID + k0 + c);
            }
            __syncthreads();
            #pragma unroll
            for (int kk = 0; kk < TK; kk += 4) {
                float4 xv = *(const float4*)(xrow + k0 + kk);
                #pragma unroll
                for (int q = 0; q < 4; ++q) {
                    float4 wg = *(const float4*)&s_wg[ic + q][kk];
                    float4 wu = *(const float4*)&s_wu[ic + q][kk];
                    ag[q] += xv.x * wg.x + xv.y * wg.y + xv.z * wg.z + xv.w * wg.w;
                    au[q] += xv.x * wu.x + xv.y * wu.y + xv.z * wu.z + xv.w * wu.w;
                }
            }
            __syncthreads();
        }
        #pragma unroll
        for (int q = 0; q < 4; ++q) {
            float g = ag[q], u = au[q];
            s_it[tok][i0 + ic + q] = (g / (1.0f + __expf(-g))) * u;
        }
    }
    __syncthreads();

    const float wscale = s_w[tok];
    for (int h0 = 0; h0 < HID; h0 += TN) {
        float ac[4] = {0.f, 0.f, 0.f, 0.f};
        for (int k0 = 0; k0 < ITR; k0 += TK) {
            #pragma unroll
            for (int j = 0; j < 2; ++j) {
                int f4 = tid + j * 256;
                int r = f4 >> 2, c = (f4 & 3) << 2;
                *(float4*)&s_wg[r][c] = *(const float4*)(dbase + (size_t)(h0 + r) * ITR + k0 + c);
            }
            __syncthreads();
            #pragma unroll
            for (int kk = 0; kk < TK; kk += 4) {
                float4 xv = *(const float4*)&s_it[tok][k0 + kk];
                #pragma unroll
                for (int q = 0; q < 4; ++q) {
                    float4 wv = *(const float4*)&s_wg[ic + q][kk];
                    ac[q] += xv.x * wv.x + xv.y * wv.y + xv.z * wv.z + xv.w * wv.w;
                }
            }
            __syncthreads();
        }
        float* orow = out + (size_t)mytok * HID + h0 + ic;
        #pragma unroll
        for (int q = 0; q < 4; ++q) atomicAdd(&orow[q], wscale * ac[q]);
    }
}

extern "C" void kernel_launch(void* const* d_in, const int* in_sizes, int n_in,
                              void* d_out, int out_size, void* d_ws, size_t ws_size,
                              hipStream_t stream) {
    const float* x    = (const float*)d_in[0];
    const int*   idx  = (const int*)d_in[1];
    const float* wts  = (const float*)d_in[2];
    const float* gate = (const float*)d_in[3];
    const float* up   = (const float*)d_in[4];
    const float* down = (const float*)d_in[5];
    float* out = (float*)d_out;

    // ---- common small region ----
    const size_t off_btok  = 256;
    const size_t off_bw    = off_btok + (size_t)NEXP * NSLOT * 4;      // 128 KB
    const size_t off_offs  = off_bw + (size_t)NEXP * NSLOT * 4;        // 128 KB
    const size_t off_smap  = off_offs + 256;
    const size_t off_tabs  = off_smap + (size_t)NSLOT * 4;             // 16 KB
    const size_t off_xb    = off_tabs + 2 * 8 * SLOTS * 4;             // 5.1 KB

    const size_t XBSZ  = (size_t)NTOK * HID * 2;          //  8.39 MB
    const size_t WSZ   = (size_t)NEXP * ITR * HID * 2;    // 33.55 MB each
    const size_t INTSZ = (size_t)(MAXTT * 128) * ITR * 2; // 10.49 MB
    const size_t PARTSZ = (size_t)(MAXTT * 128) * HID * 4; // 41.94 MB

    // ---- legacy layout (fallback tiers) ----
    const size_t off_inter_o = off_xb + XBSZ;
    const size_t off_part_o  = off_inter_o + INTSZ;
    const size_t need_mid  = off_part_o;
    const size_t need_full = off_part_o + PARTSZ;

    // ---- tier-2 bf16 layout (db aliases xb/gb-head, part aliases gb-tail/ub) ----
    const size_t off_gb2      = off_xb + XBSZ;
    const size_t off_ub2      = off_gb2 + WSZ;
    const size_t off_inter_n  = off_ub2 + WSZ;
    const size_t off_db2      = off_xb;            // dead after gu
    const size_t off_part2    = off_db2 + WSZ;     // gb tail + ub, dead after gu
    const size_t need_bf      = off_inter_n + INTSZ;   // ~86.3 MB

    // ---- tier-1 bf16 layout (all weights separate; down cvt overlapped with gu) ----
    const size_t off_gb1    = off_xb + XBSZ;
    const size_t off_ub1    = off_gb1 + WSZ;
    const size_t off_db1    = off_ub1 + WSZ;
    const size_t off_int1   = off_db1 + WSZ;
    const size_t off_part1  = off_gb1;             // gb+ub dead after gu (67.1 MB >= 41.9)
    const size_t need_bf1   = off_int1 + INTSZ;    // ~119.8 MB

    int*   counts = (int*)d_ws;
    int*   btok   = (int*)((char*)d_ws + off_btok);
    float* bwp    = (float*)((char*)d_ws + off_bw);
    int*   offs   = (int*)((char*)d_ws + off_offs);
    int*   smap   = (int*)((char*)d_ws + off_smap);
    int*   gu_tab = (int*)((char*)d_ws + off_tabs);
    int*   dn_tab = gu_tab + 8 * SLOTS;
    unsigned short* xb = (unsigned short*)((char*)d_ws + off_xb);

    if (ws_size >= need_bf1) {
        unsigned short* gb     = (unsigned short*)((char*)d_ws + off_gb1);
        unsigned short* ub     = (unsigned short*)((char*)d_ws + off_ub1);
        unsigned short* db     = (unsigned short*)((char*)d_ws + off_db1);
        unsigned short* interw = (unsigned short*)((char*)d_ws + off_int1);
        float*          part   = (float*)((char*)d_ws + off_part1);

        prep_all_k<<<dim3(PREP_BLOCKS + 1), dim3(256), 0, stream>>>(x, gate, up, idx, wts,
                                                                    xb, gb, ub,
                                                                    counts, btok, bwp, offs, smap, gu_tab, dn_tab);
        moe_gu_fused_k<<<dim3(8 * SLOTS + CVTD_BLOCKS), dim3(256), 0, stream>>>(xb, gb, ub, counts, btok, offs,
                                                                                gu_tab, interw, down, db);
        moe_down_bf_k<<<dim3(8 * SLOTS), dim3(256), 0, stream>>>(interw, db, counts, btok, bwp, offs, dn_tab, part, 0);
        combine_k<<<dim3(NTOK * HID / 4 / 256), dim3(256), 0, stream>>>(part, smap, out);
    } else if (ws_size >= need_bf) {
        unsigned short* gb     = (unsigned short*)((char*)d_ws + off_gb2);
        unsigned short* ub     = (unsigned short*)((char*)d_ws + off_ub2);
        unsigned short* db     = (unsigned short*)((char*)d_ws + off_db2);
        unsigned short* interw = (unsigned short*)((char*)d_ws + off_inter_n);
        float*          part   = (float*)((char*)d_ws + off_part2);

        const int cvt1_blocks = (int)(((size_t)NTOK * HID / 8 + 2 * (WSZ / 16)) / 256); // 18432
        const int cvt2_blocks = (int)((WSZ / 16) / 256);                                 // 8192

        route_all_k<<<dim3(1), dim3(256), 0, stream>>>(idx, wts, counts, btok, bwp, offs, smap, gu_tab, dn_tab);
        cvt_gux_k<<<dim3(cvt1_blocks), dim3(256), 0, stream>>>(x, gate, up, xb, gb, ub);
        moe_gu_fused_k<<<dim3(8 * SLOTS), dim3(256), 0, stream>>>(xb, gb, ub, counts, btok, offs,
                                                                  gu_tab, interw, (const float*)0, (unsigned short*)0);
        cvt_dn_k<<<dim3(cvt2_blocks), dim3(256), 0, stream>>>(down, db);
        moe_down_bf_k<<<dim3(8 * SLOTS), dim3(256), 0, stream>>>(interw, db, counts, btok, bwp, offs, dn_tab, part, 0);
        combine_k<<<dim3(NTOK * HID / 4 / 256), dim3(256), 0, stream>>>(part, smap, out);
    } else if (ws_size >= need_mid) {
        const int full = (ws_size >= need_full);
        unsigned short* interw = (unsigned short*)((char*)d_ws + off_inter_o);
        float* part   = (float*)((char*)d_ws + off_part_o);
        route_all_k<<<dim3(1), dim3(256), 0, stream>>>(idx, wts, counts, btok, bwp, offs, smap, gu_tab, dn_tab);
        xconv_k<<<dim3(NTOK * HID / 4 / 256), dim3(256), 0, stream>>>(x, xb);
        if (!full) hipMemsetAsync(d_out, 0, (size_t)out_size * sizeof(float), stream);
        moe_gu_k<<<dim3(8 * SLOTS), dim3(256), 0, stream>>>(xb, gate, up, counts, btok, offs, gu_tab, interw);
        moe_down_k<<<dim3(8 * SLOTS), dim3(256), 0, stream>>>(interw, down, counts, btok, bwp, offs, dn_tab,
                                                              full ? part : out, full ? 0 : 1);
        if (full)
            combine_k<<<dim3(NTOK * HID / 4 / 256), dim3(256), 0, stream>>>(part, smap, out);
    } else {
        hipMemsetAsync(d_out, 0, (size_t)out_size * sizeof(float), stream);
        hipMemsetAsync(counts, 0, 256, stream);
        route_k<<<dim3((NSLOT + 255) / 256), dim3(256), 0, stream>>>(idx, wts, counts, btok, bwp);
        moe_k<<<dim3(NEXP * MAXTILES), dim3(256), 0, stream>>>(x, gate, up, down, counts, btok, bwp, out);
    }
}

// Round 4
// 322.515 us; speedup vs baseline: 1.3656x; 1.0700x over previous
//
#include <hip/hip_runtime.h>
#include <math.h>

#define HID 2048
#define ITR 1024
#define NEXP 8
#define TOPK 2
#define NTOK 2048
#define NSLOT (NTOK * TOPK)
#define MAXTT 40        // max 128-row tiles across experts (bound 4096/128+7=39)
#define SLOTS 80        // per-XCD slot count for block tables (bound 2*39=78)
#define CVTD_BLOCKS 1024
#define PREP_BLOCKS 4096

typedef __attribute__((ext_vector_type(8))) short short8;
typedef __attribute__((ext_vector_type(4))) float f32x4;

__device__ __forceinline__ unsigned short f2bf(float f) {
    unsigned u = __float_as_uint(f);
    u += 0x7FFFu + ((u >> 16) & 1u);
    return (unsigned short)(u >> 16);
}

// async global->LDS, 16B per lane; dest must be wave-uniform base (+lane*16 by HW)
#define GLL16(g, l) \
    __builtin_amdgcn_global_load_lds((const __attribute__((address_space(1))) unsigned int*)(g), \
                                     (__attribute__((address_space(3))) unsigned int*)(l), 16, 0, 0)

// ---------------- routing device helper (single block's worth of work) ----------------
__device__ __forceinline__ void route_body(const int* __restrict__ idx,
                                           const float* __restrict__ wts,
                                           int* __restrict__ counts_g,
                                           int* __restrict__ btok,
                                           float* __restrict__ bw,
                                           int* __restrict__ offs_g,
                                           int* __restrict__ slotmap,
                                           int* __restrict__ gu_tab,
                                           int* __restrict__ dn_tab) {
    __shared__ int h[NEXP], nt[NEXP], pre[NEXP], base[NEXP], cur[NEXP];
    const int tid = threadIdx.x;
    if (tid < NEXP) { h[tid] = 0; cur[tid] = 0; }
    __syncthreads();
    for (int s = tid; s < NSLOT; s += 256) atomicAdd(&h[idx[s]], 1);
    __syncthreads();
    if (tid == 0) {
        int a = 0;
        for (int e = 0; e < NEXP; ++e) {
            base[e] = a; counts_g[e] = h[e]; offs_g[e] = a;
            int t = (h[e] + 127) >> 7; nt[e] = t; a += t << 7;
        }
        int p = 0;
        for (int e = 0; e < NEXP; ++e) { pre[e] = p; p += nt[e]; }
    }
    __syncthreads();
    for (int s = tid; s < NSLOT; s += 256) {
        int e = idx[s];
        int p = atomicAdd(&cur[e], 1);
        btok[e * NSLOT + p] = s >> 1;          // token id (TOPK=2)
        bw[e * NSLOT + p] = wts[s];
        slotmap[s] = base[e] + p;              // global compact row
    }
    for (int i = tid; i < 8 * SLOTS; i += 256) { gu_tab[i] = -1; dn_tab[i] = -1; }
    __syncthreads();
    if (tid < 128) {
        int c = tid, e = c >> 4, ib = c & 15;
        int sb = 2 * pre[e] + (ib >> 3) * nt[e];
        for (int j = 0; j < nt[e]; ++j)
            gu_tab[(sb + j) * 8 + (ib & 7)] = (e << 16) | (ib << 8) | j;
    } else if (tid < 256) {
        int c = tid - 128, e = c >> 4, ib = c & 15;
        int sb = 2 * pre[e] + (ib >> 3) * nt[e];
        for (int j = 0; j < nt[e]; ++j)
            dn_tab[(sb + j) * 8 + (ib & 7)] = (e << 16) | (ib << 8) | j;
    }
}

__global__ void route_all_k(const int* __restrict__ idx, const float* __restrict__ wts,
                            int* __restrict__ counts_g, int* __restrict__ btok,
                            float* __restrict__ bw, int* __restrict__ offs_g,
                            int* __restrict__ slotmap, int* __restrict__ gu_tab,
                            int* __restrict__ dn_tab) {
    route_body(idx, wts, counts_g, btok, bw, offs_g, slotmap, gu_tab, dn_tab);
}

// ---------------- fp32 -> bf16 conversion ----------------
__device__ __forceinline__ void cvt8(const float* __restrict__ src,
                                     unsigned short* __restrict__ dst, size_t o) {
    const float4* s4 = (const float4*)src + o * 2;
    float4 a = s4[0], b = s4[1];
    union { unsigned short s[8]; uint4 v; } r;
    r.s[0] = f2bf(a.x); r.s[1] = f2bf(a.y); r.s[2] = f2bf(a.z); r.s[3] = f2bf(a.w);
    r.s[4] = f2bf(b.x); r.s[5] = f2bf(b.y); r.s[6] = f2bf(b.z); r.s[7] = f2bf(b.w);
    ((uint4*)dst)[o] = r.v;
}

// tier-1 prep: routing (block 0) + grid-stride convert of x, gate, up
__global__ void prep_all_k(const float* __restrict__ x, const float* __restrict__ g,
                           const float* __restrict__ u,
                           const int* __restrict__ idx, const float* __restrict__ wts,
                           unsigned short* __restrict__ xb, unsigned short* __restrict__ gb,
                           unsigned short* __restrict__ ub,
                           int* __restrict__ counts_g, int* __restrict__ btok,
                           float* __restrict__ bw, int* __restrict__ offs_g,
                           int* __restrict__ slotmap, int* __restrict__ gu_tab,
                           int* __restrict__ dn_tab) {
    if (blockIdx.x == 0) {
        route_body(idx, wts, counts_g, btok, bw, offs_g, slotmap, gu_tab, dn_tab);
        return;
    }
    const size_t X8 = (size_t)NTOK * HID / 8;
    const size_t W8 = (size_t)NEXP * ITR * HID / 8;
    const size_t TOT = X8 + 2 * W8;
    const size_t stride = (size_t)PREP_BLOCKS * 256;
    size_t j = (size_t)(blockIdx.x - 1) * 256 + threadIdx.x;
    for (; j + stride < TOT; j += 2 * stride) {
        size_t j2 = j + stride;
        if (j < X8)                cvt8(x, xb, j);
        else if (j < X8 + W8)      cvt8(g, gb, j - X8);
        else                       cvt8(u, ub, j - X8 - W8);
        if (j2 < X8)               cvt8(x, xb, j2);
        else if (j2 < X8 + W8)     cvt8(g, gb, j2 - X8);
        else                       cvt8(u, ub, j2 - X8 - W8);
    }
    if (j < TOT) {
        if (j < X8)                cvt8(x, xb, j);
        else if (j < X8 + W8)      cvt8(g, gb, j - X8);
        else                       cvt8(u, ub, j - X8 - W8);
    }
}

// tier-2 conversion kernels
__global__ void cvt_gux_k(const float* __restrict__ x, const float* __restrict__ g,
                          const float* __restrict__ u,
                          unsigned short* __restrict__ xb, unsigned short* __restrict__ gb,
                          unsigned short* __restrict__ ub) {
    size_t j = (size_t)blockIdx.x * 256 + threadIdx.x;
    const size_t X8 = (size_t)NTOK * HID / 8;
    const size_t W8 = (size_t)NEXP * ITR * HID / 8;
    if (j < X8)           cvt8(x, xb, j);
    else if (j < X8 + W8) cvt8(g, gb, j - X8);
    else                  cvt8(u, ub, j - X8 - W8);
}

__global__ void cvt_dn_k(const float* __restrict__ d, unsigned short* __restrict__ db) {
    size_t j = (size_t)blockIdx.x * 256 + threadIdx.x;
    cvt8(d, db, j);
}

// combine: out[t] = part[slot0[t]] + part[slot1[t]]  (weights already applied)
__global__ void combine_k(const float* __restrict__ part,
                          const int* __restrict__ slotmap,
                          float* __restrict__ out) {
    int gid = blockIdx.x * 256 + threadIdx.x;
    int t = gid >> 9;
    int c = gid & 511;
    int s0 = slotmap[t * 2], s1 = slotmap[t * 2 + 1];
    float4 a = ((const float4*)part)[(size_t)s0 * 512 + c];
    float4 b = ((const float4*)part)[(size_t)s1 * 512 + c];
    float4 r; r.x = a.x + b.x; r.y = a.y + b.y; r.z = a.z + b.z; r.w = a.w + b.w;
    ((float4*)out)[gid] = r;
}

// ================= bf16 MFMA path: 512-thread / 8-wave blocks, M=128 tiles =================
#define BK 64

// Stage 1: M=128 slots x N=64 inter cols (gate & up), K=2048.
// grid = 8*SLOTS MFMA blocks via gu_tab (512 thr), + CVTD_BLOCKS trailing blocks converting down.
__launch_bounds__(512)
__global__ void moe_gu_fused_k(const unsigned short* __restrict__ xb,
                               const unsigned short* __restrict__ gateb,
                               const unsigned short* __restrict__ upb,
                               const int* __restrict__ counts,
                               const int* __restrict__ btok,
                               const int* __restrict__ off,
                               const int* __restrict__ gu_tab,
                               unsigned short* __restrict__ interw,
                               const float* __restrict__ down,
                               unsigned short* __restrict__ db) {
    if (blockIdx.x >= 8 * SLOTS) {
        // grid-stride down-conversion: D8 = NEXP*HID*ITR/8 uint4-groups
        const size_t D8 = (size_t)NEXP * HID * ITR / 8;
        const size_t stride = (size_t)CVTD_BLOCKS * 512;
        size_t j = (size_t)(blockIdx.x - 8 * SLOTS) * 512 + threadIdx.x;
        for (; j + stride < D8; j += 2 * stride) {
            cvt8(down, db, j);
            cvt8(down, db, j + stride);
        }
        if (j < D8) cvt8(down, db, j);
        return;
    }
    const int v = gu_tab[blockIdx.x];
    if (v < 0) return;
    const int e    = v >> 16;
    const int iblk = (v >> 8) & 255;
    const int tile = v & 255;
    const int n = counts[e];

    __shared__ unsigned short s_a[128 * 64];   // [row][64 bf16], 128B rows, XOR-swizzled
    __shared__ unsigned short s_bg[64 * 64];
    __shared__ unsigned short s_bu[64 * 64];
    __shared__ int s_tok[128];

    const int tid = threadIdx.x;
    if (tid < 128) {
        int tt = tile * 128 + tid;
        s_tok[tid] = btok[e * NSLOT + (tt < n ? tt : n - 1)];
    }
    __syncthreads();

    const int w = tid >> 6;
    const int lane = tid & 63;

    // A staging: 2 insts x 512 threads x 16B = 128 rows x 128B
    const char* asrc[2]; unsigned short* adst[2];
    #pragma unroll
    for (int t = 0; t < 2; ++t) {
        int c = tid + t * 512;
        int r = c >> 3;
        unsigned sw = ((unsigned)(c & 7) * 16u) ^ (((unsigned)r & 7u) << 4);
        asrc[t] = (const char*)xb + (size_t)s_tok[r] * (HID * 2) + sw;
        adst[t] = s_a + (size_t)(t * 512 + w * 64) * 8;   // wave-uniform base
    }
    // B staging: 1 inst each for gate/up = 64 rows x 128B each
    const char* gB = (const char*)gateb + ((size_t)e * ITR + (size_t)iblk * 64) * (HID * 2);
    const char* uB = (const char*)upb   + ((size_t)e * ITR + (size_t)iblk * 64) * (HID * 2);
    const char* gsrc; const char* usrc;
    unsigned short* gdst; unsigned short* udst;
    {
        int c = tid;
        int r = c >> 3;
        unsigned sw = ((unsigned)(c & 7) * 16u) ^ (((unsigned)r & 7u) << 4);
        gsrc = gB + (size_t)r * (HID * 2) + sw;
        usrc = uB + (size_t)r * (HID * 2) + sw;
        gdst = s_bg + (size_t)(w * 64) * 8;
        udst = s_bu + (size_t)(w * 64) * 8;
    }

    // 8 waves: 4 along M (wm), 2 along N (wn)
    const int wm = (w & 3) * 32, wn = (w >> 2) * 32;
    const int l15 = lane & 15, quad = lane >> 4;

    f32x4 accg[2][2], accu[2][2];
    #pragma unroll
    for (int m = 0; m < 2; ++m)
        #pragma unroll
        for (int nn = 0; nn < 2; ++nn) {
            accg[m][nn] = (f32x4){0.f, 0.f, 0.f, 0.f};
            accu[m][nn] = (f32x4){0.f, 0.f, 0.f, 0.f};
        }

    for (int k0 = 0; k0 < HID; k0 += BK) {
        const int kb0 = k0 * 2;
        #pragma unroll
        for (int t = 0; t < 2; ++t) GLL16(asrc[t] + kb0, adst[t]);
        GLL16(gsrc + kb0, gdst);
        GLL16(usrc + kb0, udst);
        __syncthreads();   // compiler-managed drain: LDS tile ready
        #pragma unroll
        for (int kk = 0; kk < 2; ++kk) {
            const unsigned kbyte = (unsigned)(kk * 64 + quad * 16);
            short8 af[2], bg[2], bu[2];
            #pragma unroll
            for (int m = 0; m < 2; ++m) {
                unsigned r = (unsigned)(wm + m * 16 + l15);
                af[m] = *(const short8*)&s_a[r * 64 + ((kbyte ^ ((r & 7u) << 4)) >> 1)];
            }
            #pragma unroll
            for (int nn = 0; nn < 2; ++nn) {
                unsigned r = (unsigned)(wn + nn * 16 + l15);
                unsigned co = (kbyte ^ ((r & 7u) << 4)) >> 1;
                bg[nn] = *(const short8*)&s_bg[r * 64 + co];
                bu[nn] = *(const short8*)&s_bu[r * 64 + co];
            }
            #pragma unroll
            for (int m = 0; m < 2; ++m)
                #pragma unroll
                for (int nn = 0; nn < 2; ++nn) {
                    accg[m][nn] = __builtin_amdgcn_mfma_f32_16x16x32_bf16(af[m], bg[nn], accg[m][nn], 0, 0, 0);
                    accu[m][nn] = __builtin_amdgcn_mfma_f32_16x16x32_bf16(af[m], bu[nn], accu[m][nn], 0, 0, 0);
                }
        }
        __syncthreads();
    }

    const int pos0 = off[e] + tile * 128;
    #pragma unroll
    for (int m = 0; m < 2; ++m) {
        #pragma unroll
        for (int nn = 0; nn < 2; ++nn) {
            int col = iblk * 64 + wn + nn * 16 + l15;
            #pragma unroll
            for (int r = 0; r < 4; ++r) {
                int row = wm + m * 16 + quad * 4 + r;
                float g = accg[m][nn][r], u = accu[m][nn][r];
                float s = g / (1.0f + __expf(-g));
                interw[(size_t)(pos0 + row) * ITR + col] = f2bf(s * u);
            }
        }
    }
}

// Stage 2: M=128 slots x N=128 hid cols, K=1024. grid = 8*SLOTS via dn_tab, 512 thr
__launch_bounds__(512)
__global__ void moe_down_bf_k(const unsigned short* __restrict__ interw,
                              const unsigned short* __restrict__ downb,
                              const int* __restrict__ counts,
                              const int* __restrict__ btok,
                              const float* __restrict__ bw,
                              const int* __restrict__ off,
                              const int* __restrict__ dn_tab,
                              float* __restrict__ dst,
                              int mode) {
    const int v = dn_tab[blockIdx.x];
    if (v < 0) return;
    const int e    = v >> 16;
    const int hblk = (v >> 8) & 255;
    const int tile = v & 255;
    const int n = counts[e];

    __shared__ unsigned short s_a[128 * 64];
    __shared__ unsigned short s_b[128 * 64];
    __shared__ int s_tok[128];
    __shared__ float s_w[128];

    const int tid = threadIdx.x;
    if (tid < 128) {
        int tt = tile * 128 + tid;
        bool vv = tt < n;
        s_tok[tid] = btok[e * NSLOT + (vv ? tt : n - 1)];
        s_w[tid] = vv ? bw[e * NSLOT + tt] : 0.0f;
    }
    __syncthreads();

    const int w = tid >> 6;
    const int lane = tid & 63;
    const int pos0 = off[e] + tile * 128;

    const char* asrc[2]; unsigned short* adst[2];
    const char* bsrc[2]; unsigned short* bdst[2];
    const char* dB = (const char*)downb + ((size_t)e * HID + (size_t)hblk * 128) * (ITR * 2);
    #pragma unroll
    for (int t = 0; t < 2; ++t) {
        int c = tid + t * 512;
        int r = c >> 3;
        unsigned sw = ((unsigned)(c & 7) * 16u) ^ (((unsigned)r & 7u) << 4);
        asrc[t] = (const char*)interw + (size_t)(pos0 + r) * (ITR * 2) + sw;
        bsrc[t] = dB + (size_t)r * (ITR * 2) + sw;
        adst[t] = s_a + (size_t)(t * 512 + w * 64) * 8;
        bdst[t] = s_b + (size_t)(t * 512 + w * 64) * 8;
    }

    // 8 waves: 4 along M, 2 along N (64 cols each)
    const int wm = (w & 3) * 32, wn = (w >> 2) * 64;
    const int l15 = lane & 15, quad = lane >> 4;

    f32x4 acc[2][4];
    #pragma unroll
    for (int m = 0; m < 2; ++m)
        #pragma unroll
        for (int nn = 0; nn < 4; ++nn) acc[m][nn] = (f32x4){0.f, 0.f, 0.f, 0.f};

    for (int k0 = 0; k0 < ITR; k0 += BK) {
        const int kb0 = k0 * 2;
        #pragma unroll
        for (int t = 0; t < 2; ++t) GLL16(asrc[t] + kb0, adst[t]);
        #pragma unroll
        for (int t = 0; t < 2; ++t) GLL16(bsrc[t] + kb0, bdst[t]);
        __syncthreads();
        #pragma unroll
        for (int kk = 0; kk < 2; ++kk) {
            const unsigned kbyte = (unsigned)(kk * 64 + quad * 16);
            short8 af[2], bf[4];
            #pragma unroll
            for (int m = 0; m < 2; ++m) {
                unsigned r = (unsigned)(wm + m * 16 + l15);
                af[m] = *(const short8*)&s_a[r * 64 + ((kbyte ^ ((r & 7u) << 4)) >> 1)];
            }
            #pragma unroll
            for (int nn = 0; nn < 4; ++nn) {
                unsigned r = (unsigned)(wn + nn * 16 + l15);
                bf[nn] = *(const short8*)&s_b[r * 64 + ((kbyte ^ ((r & 7u) << 4)) >> 1)];
            }
            #pragma unroll
            for (int m = 0; m < 2; ++m)
                #pragma unroll
                for (int nn = 0; nn < 4; ++nn)
                    acc[m][nn] = __builtin_amdgcn_mfma_f32_16x16x32_bf16(af[m], bf[nn], acc[m][nn], 0, 0, 0);
        }
        __syncthreads();
    }

    if (mode == 0) {
        #pragma unroll
        for (int m = 0; m < 2; ++m) {
            #pragma unroll
            for (int nn = 0; nn < 4; ++nn) {
                int col = hblk * 128 + wn + nn * 16 + l15;
                #pragma unroll
                for (int r = 0; r < 4; ++r) {
                    int row = wm + m * 16 + quad * 4 + r;
                    dst[(size_t)(pos0 + row) * HID + col] = s_w[row] * acc[m][nn][r];
                }
            }
        }
    } else {
        #pragma unroll
        for (int m = 0; m < 2; ++m) {
            #pragma unroll
            for (int nn = 0; nn < 4; ++nn) {
                int col = hblk * 128 + wn + nn * 16 + l15;
                #pragma unroll
                for (int r = 0; r < 4; ++r) {
                    int row = wm + m * 16 + quad * 4 + r;
                    atomicAdd(&dst[(size_t)s_tok[row] * HID + col], s_w[row] * acc[m][nn][r]);
                }
            }
        }
    }
}

// ================= fp32 fallback (used only if ws too small) =================
#define TT 8
#define TN 128
#define TK 16
#define WPAD 20
#define IPAD 1028
#define MAXTILES (NSLOT / TT)

__global__ void route_k(const int* __restrict__ idx,
                        const float* __restrict__ wts,
                        int* __restrict__ counts,
                        int* __restrict__ btok,
                        float* __restrict__ bw) {
    int s = blockIdx.x * blockDim.x + threadIdx.x;
    if (s >= NSLOT) return;
    int e = idx[s];
    int pos = atomicAdd(&counts[e], 1);
    btok[(size_t)e * NSLOT + pos] = s / TOPK;
    bw[(size_t)e * NSLOT + pos] = wts[s];
}

__launch_bounds__(256)
__global__ void moe_k(const float* __restrict__ x,
                      const float* __restrict__ gate,
                      const float* __restrict__ up,
                      const float* __restrict__ down,
                      const int* __restrict__ counts,
                      const int* __restrict__ btok,
                      const float* __restrict__ bw,
                      float* __restrict__ out) {
    const int e = blockIdx.x / MAXTILES;
    const int tile = blockIdx.x % MAXTILES;
    const int n = counts[e];
    const int t0 = tile * TT;
    if (t0 >= n) return;

    __shared__ float s_wg[TN][WPAD];
    __shared__ float s_wu[TN][WPAD];
    __shared__ float s_it[TT][IPAD];
    __shared__ int   s_tok[TT];
    __shared__ float s_w[TT];

    const int tid = threadIdx.x;
    if (tid < TT) {
        int tt = t0 + tid;
        bool v = tt < n;
        s_tok[tid] = btok[(size_t)e * NSLOT + (v ? tt : t0)];
        s_w[tid] = v ? bw[(size_t)e * NSLOT + tt] : 0.0f;
    }
    __syncthreads();

    const int tok = tid >> 5;
    const int ic  = (tid & 31) << 2;
    const int mytok = s_tok[tok];
    const float* xrow = x + (size_t)mytok * HID;
    const float* gbase = gate + (size_t)e * ITR * HID;
    const float* ubase = up   + (size_t)e * ITR * HID;
    const float* dbase = down + (size_t)e * HID * ITR;

    for (int i0 = 0; i0 < ITR; i0 += TN) {
        float ag[4] = {0.f, 0.f, 0.f, 0.f};
        float au[4] = {0.f, 0.f, 0.f, 0.f};
        for (int k0 = 0; k0 < HID; k0 += TK) {
            #pragma unroll
            for (int j = 0; j < 2; ++j) {
                int f4 = tid + j * 256;
                int r = f4 >> 2, c = (f4 & 3) << 2;
                *(float4*)&s_wg[r][c] = *(const float4*)(gbase + (size_t)(i0 + r) * HID + k0 + c);
                *(float4*)&s_wu[r][c] = *(const float4*)(ubase + (size_t)(i0 + r) * HID + k0 + c);
            }
            __syncthreads();
            #pragma unroll
            for (int kk = 0; kk < TK; kk += 4) {
                float4 xv = *(const float4*)(xrow + k0 + kk);
                #pragma unroll
                for (int q = 0; q < 4; ++q) {
                    float4 wg = *(const float4*)&s_wg[ic + q][kk];
                    float4 wu = *(const float4*)&s_wu[ic + q][kk];
                    ag[q] += xv.x * wg.x + xv.y * wg.y + xv.z * wg.z + xv.w * wg.w;
                    au[q] += xv.x * wu.x + xv.y * wu.y + xv.z * wu.z + xv.w * wu.w;
                }
            }
            __syncthreads();
        }
        #pragma unroll
        for (int q = 0; q < 4; ++q) {
            float g = ag[q], u = au[q];
            s_it[tok][i0 + ic + q] = (g / (1.0f + __expf(-g))) * u;
        }
    }
    __syncthreads();

    const float wscale = s_w[tok];
    for (int h0 = 0; h0 < HID; h0 += TN) {
        float ac[4] = {0.f, 0.f, 0.f, 0.f};
        for (int k0 = 0; k0 < ITR; k0 += TK) {
            #pragma unroll
            for (int j = 0; j < 2; ++j) {
                int f4 = tid + j * 256;
                int r = f4 >> 2, c = (f4 & 3) << 2;
                *(float4*)&s_wg[r][c] = *(const float4*)(dbase + (size_t)(h0 + r) * ITR + k0 + c);
            }
            __syncthreads();
            #pragma unroll
            for (int kk = 0; kk < TK; kk += 4) {
                float4 xv = *(const float4*)&s_it[tok][k0 + kk];
                #pragma unroll
                for (int q = 0; q < 4; ++q) {
                    float4 wv = *(const float4*)&s_wg[ic + q][kk];
                    ac[q] += xv.x * wv.x + xv.y * wv.y + xv.z * wv.z + xv.w * wv.w;
                }
            }
            __syncthreads();
        }
        float* orow = out + (size_t)mytok * HID + h0 + ic;
        #pragma unroll
        for (int q = 0; q < 4; ++q) atomicAdd(&orow[q], wscale * ac[q]);
    }
}

extern "C" void kernel_launch(void* const* d_in, const int* in_sizes, int n_in,
                              void* d_out, int out_size, void* d_ws, size_t ws_size,
                              hipStream_t stream) {
    const float* x    = (const float*)d_in[0];
    const int*   idx  = (const int*)d_in[1];
    const float* wts  = (const float*)d_in[2];
    const float* gate = (const float*)d_in[3];
    const float* up   = (const float*)d_in[4];
    const float* down = (const float*)d_in[5];
    float* out = (float*)d_out;

    // ---- common small region ----
    const size_t off_btok  = 256;
    const size_t off_bw    = off_btok + (size_t)NEXP * NSLOT * 4;      // 128 KB
    const size_t off_offs  = off_bw + (size_t)NEXP * NSLOT * 4;        // 128 KB
    const size_t off_smap  = off_offs + 256;
    const size_t off_tabs  = off_smap + (size_t)NSLOT * 4;             // 16 KB
    const size_t off_xb    = off_tabs + 2 * 8 * SLOTS * 4;             // 5.1 KB

    const size_t XBSZ  = (size_t)NTOK * HID * 2;          //  8.39 MB
    const size_t WSZ   = (size_t)NEXP * ITR * HID * 2;    // 33.55 MB each
    const size_t INTSZ = (size_t)(MAXTT * 128) * ITR * 2; // 10.49 MB

    // ---- tier-2 bf16 layout (db aliases xb/gb-head, part aliases gb-tail/ub) ----
    const size_t off_gb2      = off_xb + XBSZ;
    const size_t off_ub2      = off_gb2 + WSZ;
    const size_t off_inter_n  = off_ub2 + WSZ;
    const size_t off_db2      = off_xb;            // dead after gu
    const size_t off_part2    = off_db2 + WSZ;     // gb tail + ub, dead after gu
    const size_t need_bf      = off_inter_n + INTSZ;   // ~86.3 MB

    // ---- tier-1 bf16 layout (all weights separate; down cvt overlapped with gu) ----
    const size_t off_gb1    = off_xb + XBSZ;
    const size_t off_ub1    = off_gb1 + WSZ;
    const size_t off_db1    = off_ub1 + WSZ;
    const size_t off_int1   = off_db1 + WSZ;
    const size_t off_part1  = off_gb1;             // gb+ub dead after gu (67.1 MB >= 41.9)
    const size_t need_bf1   = off_int1 + INTSZ;    // ~119.8 MB

    int*   counts = (int*)d_ws;
    int*   btok   = (int*)((char*)d_ws + off_btok);
    float* bwp    = (float*)((char*)d_ws + off_bw);
    int*   offs   = (int*)((char*)d_ws + off_offs);
    int*   smap   = (int*)((char*)d_ws + off_smap);
    int*   gu_tab = (int*)((char*)d_ws + off_tabs);
    int*   dn_tab = gu_tab + 8 * SLOTS;
    unsigned short* xb = (unsigned short*)((char*)d_ws + off_xb);

    if (ws_size >= need_bf1) {
        unsigned short* gb     = (unsigned short*)((char*)d_ws + off_gb1);
        unsigned short* ub     = (unsigned short*)((char*)d_ws + off_ub1);
        unsigned short* db     = (unsigned short*)((char*)d_ws + off_db1);
        unsigned short* interw = (unsigned short*)((char*)d_ws + off_int1);
        float*          part   = (float*)((char*)d_ws + off_part1);

        prep_all_k<<<dim3(PREP_BLOCKS + 1), dim3(256), 0, stream>>>(x, gate, up, idx, wts,
                                                                    xb, gb, ub,
                                                                    counts, btok, bwp, offs, smap, gu_tab, dn_tab);
        moe_gu_fused_k<<<dim3(8 * SLOTS + CVTD_BLOCKS), dim3(512), 0, stream>>>(xb, gb, ub, counts, btok, offs,
                                                                                gu_tab, interw, down, db);
        moe_down_bf_k<<<dim3(8 * SLOTS), dim3(512), 0, stream>>>(interw, db, counts, btok, bwp, offs, dn_tab, part, 0);
        combine_k<<<dim3(NTOK * HID / 4 / 256), dim3(256), 0, stream>>>(part, smap, out);
    } else if (ws_size >= need_bf) {
        unsigned short* gb     = (unsigned short*)((char*)d_ws + off_gb2);
        unsigned short* ub     = (unsigned short*)((char*)d_ws + off_ub2);
        unsigned short* db     = (unsigned short*)((char*)d_ws + off_db2);
        unsigned short* interw = (unsigned short*)((char*)d_ws + off_inter_n);
        float*          part   = (float*)((char*)d_ws + off_part2);

        const int cvt1_blocks = (int)(((size_t)NTOK * HID / 8 + 2 * (WSZ / 16)) / 256); // 18432
        const int cvt2_blocks = (int)((WSZ / 16) / 256);                                 // 8192

        route_all_k<<<dim3(1), dim3(256), 0, stream>>>(idx, wts, counts, btok, bwp, offs, smap, gu_tab, dn_tab);
        cvt_gux_k<<<dim3(cvt1_blocks), dim3(256), 0, stream>>>(x, gate, up, xb, gb, ub);
        moe_gu_fused_k<<<dim3(8 * SLOTS), dim3(512), 0, stream>>>(xb, gb, ub, counts, btok, offs,
                                                                  gu_tab, interw, (const float*)0, (unsigned short*)0);
        cvt_dn_k<<<dim3(cvt2_blocks), dim3(256), 0, stream>>>(down, db);
        moe_down_bf_k<<<dim3(8 * SLOTS), dim3(512), 0, stream>>>(interw, db, counts, btok, bwp, offs, dn_tab, part, 0);
        combine_k<<<dim3(NTOK * HID / 4 / 256), dim3(256), 0, stream>>>(part, smap, out);
    } else {
        hipMemsetAsync(d_out, 0, (size_t)out_size * sizeof(float), stream);
        hipMemsetAsync(counts, 0, 256, stream);
        route_k<<<dim3((NSLOT + 255) / 256), dim3(256), 0, stream>>>(idx, wts, counts, btok, bwp);
        moe_k<<<dim3(NEXP * MAXTILES), dim3(256), 0, stream>>>(x, gate, up, down, counts, btok, bwp, out);
    }
}